// Round 1
// baseline (532.131 us; speedup 1.0000x reference)
//
#include <hip/hip_runtime.h>
#include <math.h>

// Problem constants
#define kB 8
#define kA 128
#define kD 256
#define kF 2048
// hd = 2*kD/8 = 64 (content/pos head dim), vhd = 32 (value head dim)
// scale = 1/sqrt(64) = 0.125

// ---------------------------------------------------------------------------
// Shared 8-row x 256-col GEMM tile body: Y[r0+r][t] = sum_c X[r0+r][c]*W[c][t] + b[t]
// X: (1024,256), W: (256,256) row-major, block = 256 threads.
// ---------------------------------------------------------------------------
__device__ __forceinline__ void gemm8_256(const float* __restrict__ X,
                                          const float* __restrict__ W,
                                          const float* __restrict__ bias,
                                          float* __restrict__ Y,
                                          int r0, int t, float* xs)
{
    for (int i = 0; i < 8; ++i) xs[i * 256 + t] = X[(r0 + i) * 256 + t];
    __syncthreads();
    float acc[8] = {0.f, 0.f, 0.f, 0.f, 0.f, 0.f, 0.f, 0.f};
    for (int c = 0; c < 256; c += 4) {
        float w0 = W[(c + 0) * 256 + t];
        float w1 = W[(c + 1) * 256 + t];
        float w2 = W[(c + 2) * 256 + t];
        float w3 = W[(c + 3) * 256 + t];
#pragma unroll
        for (int r = 0; r < 8; ++r) {
            float4 xv = *(const float4*)&xs[r * 256 + c];
            acc[r] += xv.x * w0 + xv.y * w1 + xv.z * w2 + xv.w * w3;
        }
    }
    float bv = bias[t];
#pragma unroll
    for (int r = 0; r < 8; ++r) Y[(r0 + r) * 256 + t] = acc[r] + bv;
}

// Kernel 1: q = src@Wq+bq ; k_base = src@Wk+bk ; q_pos = spe@Wqp+bqp
__global__ __launch_bounds__(256) void proj3_kernel(
    const float* __restrict__ src, const float* __restrict__ spe,
    const float* __restrict__ Wq, const float* __restrict__ bq,
    const float* __restrict__ Wk, const float* __restrict__ bk,
    const float* __restrict__ Wqp, const float* __restrict__ bqp,
    float* __restrict__ q, float* __restrict__ kb, float* __restrict__ qpos)
{
    __shared__ float xs[8 * 256];
    const float *X, *W, *B;
    float* Y;
    if (blockIdx.y == 0)      { X = src; W = Wq;  B = bq;  Y = q; }
    else if (blockIdx.y == 1) { X = src; W = Wk;  B = bk;  Y = kb; }
    else                      { X = spe; W = Wqp; B = bqp; Y = qpos; }
    gemm8_256(X, W, B, Y, blockIdx.x * 8, threadIdx.x, xs);
}

// Kernel 2: v_base = k_base@Wv + bv  (dependency on kernel 1)
__global__ __launch_bounds__(256) void projv_kernel(
    const float* __restrict__ kb, const float* __restrict__ Wv,
    const float* __restrict__ bv, float* __restrict__ vb)
{
    __shared__ float xs[8 * 256];
    gemm8_256(kb, Wv, bv, vb, blockIdx.x * 8, threadIdx.x, xs);
}

// ---------------------------------------------------------------------------
// Kernel 3: fused attention + residual + LN1, one block per (b, q) pair.
//   u[h][c]    = sum_e qp[h*64+e] * Wkp[c][h*64+e]         (query-side projection)
//   s_pos[h,k] = sum_c R[k,c]*u[h][c] + qp_h . bkp_h
//   s_con[h,k] = q_h . k_base[k]_h
//   attn       = softmax(scale * s)
//   r[h][c]    = sum_k attn[h,k]*R[k,c]
//   out[h*32+e]= sum_k attn[h,k]*v_base[k,h*32+e] + (r[h] @ Wvp)[h*32+e] + bvp
//   x = LN1(src + out)
// ---------------------------------------------------------------------------
__global__ __launch_bounds__(256) void attn_kernel(
    const float* __restrict__ src, const float* __restrict__ rel,
    const float* __restrict__ q, const float* __restrict__ qpos,
    const float* __restrict__ kb, const float* __restrict__ vb,
    const float* __restrict__ Wkp, const float* __restrict__ bkp,
    const float* __restrict__ Wvp, const float* __restrict__ bvp,
    const float* __restrict__ g1, const float* __restrict__ be1,
    float* __restrict__ x_out)
{
    const int t  = threadIdx.x;
    const int qi = blockIdx.x;   // 0..127
    const int b  = blockIdx.y;   // 0..7
    const int row = b * kA + qi;

    __shared__ float q_lds[256];
    __shared__ float qp_lds[256];
    __shared__ float u_lds[4][256];
    __shared__ float beta_lds[4];
    __shared__ float sp_tmp[4][128];
    __shared__ float attn_t[128][8];   // [k][head], scores then attn (transposed)
    __shared__ float r_lds[8][256];
    __shared__ float redA[4], redB[4];

    q_lds[t]  = q[row * 256 + t];
    qp_lds[t] = qpos[row * 256 + t];
    __syncthreads();

    // ---- Phase 1: u[h][t] over Wkp row t ----
    {
        const float4* wr4 = (const float4*)(Wkp + t * 256);
        const float4* qp4 = (const float4*)qp_lds;
        float acc[4] = {0.f, 0.f, 0.f, 0.f};
#pragma unroll 4
        for (int i = 0; i < 16; ++i) {
#pragma unroll
            for (int hp = 0; hp < 4; ++hp) {
                float4 w  = wr4[hp * 16 + i];
                float4 qv = qp4[hp * 16 + i];
                acc[hp] += qv.x * w.x + qv.y * w.y + qv.z * w.z + qv.w * w.w;
            }
        }
#pragma unroll
        for (int hp = 0; hp < 4; ++hp) u_lds[hp][t] = acc[hp];
        if (t < 4) {   // beta[h] = qp_h . bkp_h
            float s = 0.f;
            for (int e = 0; e < 64; ++e) s += qp_lds[t * 64 + e] * bkp[t * 64 + e];
            beta_lds[t] = s;
        }
    }
    __syncthreads();

    // ---- Phase 2: content scores (heads 0..3) ----
    for (int i = t; i < 512; i += 256) {
        int h = i >> 7, k = i & 127;
        const float4* kr4 = (const float4*)(kb + (b * kA + k) * 256 + h * 64);
        const float4* qr4 = (const float4*)(q_lds + h * 64);
        float s = 0.f;
#pragma unroll
        for (int e = 0; e < 16; ++e) {
            float4 kv = kr4[e], qv = qr4[e];
            s += qv.x * kv.x + qv.y * kv.y + qv.z * kv.z + qv.w * kv.w;
        }
        attn_t[k][h] = s * 0.125f;
    }

    // ---- Phase 3: pos scores (heads 4..7), split over c halves ----
    {
        int k = t & 127, half = t >> 7;
        const float4* rr4 = (const float4*)(rel + ((b * kA + qi) * kA + k) * 256 + half * 128);
        float acc[4] = {0.f, 0.f, 0.f, 0.f};
        for (int i = 0; i < 32; ++i) {
            float4 rv = rr4[i];
            int c4 = half * 32 + i;
#pragma unroll
            for (int hp = 0; hp < 4; ++hp) {
                float4 uv = ((const float4*)u_lds[hp])[c4];
                acc[hp] += rv.x * uv.x + rv.y * uv.y + rv.z * uv.z + rv.w * uv.w;
            }
        }
        if (half == 0) {
#pragma unroll
            for (int hp = 0; hp < 4; ++hp) sp_tmp[hp][k] = acc[hp];
        }
        __syncthreads();
        if (half == 1) {
#pragma unroll
            for (int hp = 0; hp < 4; ++hp)
                attn_t[k][4 + hp] = (sp_tmp[hp][k] + acc[hp] + beta_lds[hp]) * 0.125f;
        }
    }
    __syncthreads();

    // ---- Phase 4: softmax per head over k (head = t>>5, 32 lanes x 4 k each) ----
    {
        int h = t >> 5, l = t & 31;
        float v0 = attn_t[l][h], v1 = attn_t[l + 32][h];
        float v2 = attn_t[l + 64][h], v3 = attn_t[l + 96][h];
        float m = fmaxf(fmaxf(v0, v1), fmaxf(v2, v3));
#pragma unroll
        for (int sh = 16; sh; sh >>= 1) m = fmaxf(m, __shfl_xor(m, sh, 64));
        v0 = __expf(v0 - m); v1 = __expf(v1 - m);
        v2 = __expf(v2 - m); v3 = __expf(v3 - m);
        float s = v0 + v1 + v2 + v3;
#pragma unroll
        for (int sh = 16; sh; sh >>= 1) s += __shfl_xor(s, sh, 64);
        float inv = 1.0f / s;
        attn_t[l][h] = v0 * inv; attn_t[l + 32][h] = v1 * inv;
        attn_t[l + 64][h] = v2 * inv; attn_t[l + 96][h] = v3 * inv;
    }
    __syncthreads();

    // ---- Phase 5: r[h][c] (attention-weighted R) + content PV, coalesced over t=c ----
    float cacc = 0.f;
    {
        const int ht = t >> 5;
        float racc[8] = {0.f, 0.f, 0.f, 0.f, 0.f, 0.f, 0.f, 0.f};
        const float* relbase = rel + (size_t)(b * kA + qi) * kA * 256 + t;
        const float* vbase   = vb + b * kA * 256 + t;
        for (int k = 0; k < 128; ++k) {
            float rv = relbase[k * 256];
            float vv = vbase[k * 256];
            float4 a0 = *(const float4*)&attn_t[k][0];
            float4 a1 = *(const float4*)&attn_t[k][4];
            racc[0] += a0.x * rv; racc[1] += a0.y * rv;
            racc[2] += a0.z * rv; racc[3] += a0.w * rv;
            racc[4] += a1.x * rv; racc[5] += a1.y * rv;
            racc[6] += a1.z * rv; racc[7] += a1.w * rv;
            cacc += attn_t[k][ht] * vv;
        }
#pragma unroll
        for (int h = 0; h < 8; ++h) r_lds[h][t] = racc[h];
    }
    __syncthreads();

    // ---- Phase 6: pos output = r[h] @ Wvp column t, + bias ----
    float out_val;
    {
        const int h = t >> 5;
        const float* wvp = Wvp + t;
        const float4* rrow = (const float4*)r_lds[h];
        float pacc = 0.f;
        for (int c = 0; c < 256; c += 4) {
            float4 r4 = rrow[c >> 2];
            pacc += r4.x * wvp[(c + 0) * 256] + r4.y * wvp[(c + 1) * 256]
                  + r4.z * wvp[(c + 2) * 256] + r4.w * wvp[(c + 3) * 256];
        }
        out_val = cacc + pacc + bvp[t];
    }

    // ---- Phase 7: residual + LayerNorm1 ----
    {
        float y = src[row * 256 + t] + out_val;
        float s1 = y, s2 = y * y;
#pragma unroll
        for (int sh = 32; sh; sh >>= 1) {
            s1 += __shfl_xor(s1, sh, 64);
            s2 += __shfl_xor(s2, sh, 64);
        }
        if ((t & 63) == 0) { redA[t >> 6] = s1; redB[t >> 6] = s2; }
        __syncthreads();
        s1 = redA[0] + redA[1] + redA[2] + redA[3];
        s2 = redB[0] + redB[1] + redB[2] + redB[3];
        float mean = s1 * (1.0f / 256.0f);
        float var  = fmaxf(s2 * (1.0f / 256.0f) - mean * mean, 0.0f);
        float inv  = rsqrtf(var + 1e-5f);
        x_out[row * 256 + t] = (y - mean) * inv * g1[t] + be1[t];
    }
}

// ---------------------------------------------------------------------------
// Kernel 4: h = relu(x @ W1 + b1). Block: 8 rows x 1024 cols (grid.y = col half).
// ---------------------------------------------------------------------------
__global__ __launch_bounds__(256) void ffn1_kernel(
    const float* __restrict__ x, const float* __restrict__ W1,
    const float* __restrict__ b1, float* __restrict__ h)
{
    __shared__ float xs[8 * 256];
    const int t = threadIdx.x;
    const int r0 = blockIdx.x * 8;
    const int c0 = blockIdx.y * 1024;
    for (int i = 0; i < 8; ++i) xs[i * 256 + t] = x[(r0 + i) * 256 + t];
    __syncthreads();
    float acc[8][4];
#pragma unroll
    for (int r = 0; r < 8; ++r)
#pragma unroll
        for (int j = 0; j < 4; ++j) acc[r][j] = 0.f;

    for (int c = 0; c < 256; c += 4) {
        float w[4][4];
#pragma unroll
        for (int cc = 0; cc < 4; ++cc)
#pragma unroll
            for (int j = 0; j < 4; ++j)
                w[cc][j] = W1[(c + cc) * 2048 + c0 + j * 256 + t];
#pragma unroll
        for (int r = 0; r < 8; ++r) {
            float4 xv = *(const float4*)&xs[r * 256 + c];
#pragma unroll
            for (int j = 0; j < 4; ++j)
                acc[r][j] += xv.x * w[0][j] + xv.y * w[1][j] + xv.z * w[2][j] + xv.w * w[3][j];
        }
    }
#pragma unroll
    for (int j = 0; j < 4; ++j) {
        float bv = b1[c0 + j * 256 + t];
#pragma unroll
        for (int r = 0; r < 8; ++r)
            h[(r0 + r) * 2048 + c0 + j * 256 + t] = fmaxf(acc[r][j] + bv, 0.f);
    }
}

// ---------------------------------------------------------------------------
// Kernel 5: ff = h @ W2 + b2 ; out = LN2(x + ff). Block: 4 rows (full width for LN).
// ---------------------------------------------------------------------------
__global__ __launch_bounds__(256) void ffn2_ln_kernel(
    const float* __restrict__ x, const float* __restrict__ hbuf,
    const float* __restrict__ W2, const float* __restrict__ b2,
    const float* __restrict__ g2, const float* __restrict__ be2,
    float* __restrict__ out)
{
    __shared__ float hs[4 * 512];
    __shared__ float ymem[4][256];
    __shared__ float stat[4][2];
    const int t = threadIdx.x;
    const int r0 = blockIdx.x * 4;

    float acc[4] = {0.f, 0.f, 0.f, 0.f};
    for (int cc = 0; cc < 2048; cc += 512) {
        for (int i = 0; i < 8; ++i) {
            int idx = i * 256 + t;
            int r = idx >> 9, c = idx & 511;
            hs[r * 512 + c] = hbuf[(r0 + r) * 2048 + cc + c];
        }
        __syncthreads();
        for (int c = 0; c < 512; c += 4) {
            float w0 = W2[(cc + c + 0) * 256 + t];
            float w1 = W2[(cc + c + 1) * 256 + t];
            float w2 = W2[(cc + c + 2) * 256 + t];
            float w3 = W2[(cc + c + 3) * 256 + t];
#pragma unroll
            for (int r = 0; r < 4; ++r) {
                float4 hv = *(const float4*)&hs[r * 512 + c];
                acc[r] += hv.x * w0 + hv.y * w1 + hv.z * w2 + hv.w * w3;
            }
        }
        __syncthreads();
    }
    float b2v = b2[t];
#pragma unroll
    for (int r = 0; r < 4; ++r) ymem[r][t] = x[(r0 + r) * 256 + t] + acc[r] + b2v;
    __syncthreads();

    {   // per-row mean/var: wave w handles row w>>... use t>>6 (one wave per row)
        int r = t >> 6, l = t & 63;
        float a0 = ymem[r][l], a1 = ymem[r][l + 64];
        float a2 = ymem[r][l + 128], a3 = ymem[r][l + 192];
        float s1 = a0 + a1 + a2 + a3;
        float s2 = a0 * a0 + a1 * a1 + a2 * a2 + a3 * a3;
#pragma unroll
        for (int sh = 32; sh; sh >>= 1) {
            s1 += __shfl_xor(s1, sh, 64);
            s2 += __shfl_xor(s2, sh, 64);
        }
        if (l == 0) { stat[r][0] = s1; stat[r][1] = s2; }
    }
    __syncthreads();
    float g = g2[t], be = be2[t];
#pragma unroll
    for (int r = 0; r < 4; ++r) {
        float mean = stat[r][0] * (1.0f / 256.0f);
        float var  = fmaxf(stat[r][1] * (1.0f / 256.0f) - mean * mean, 0.0f);
        float inv  = rsqrtf(var + 1e-5f);
        out[(r0 + r) * 256 + t] = (ymem[r][t] - mean) * inv * g + be;
    }
}

// ---------------------------------------------------------------------------
extern "C" void kernel_launch(void* const* d_in, const int* in_sizes, int n_in,
                              void* d_out, int out_size, void* d_ws, size_t ws_size,
                              hipStream_t stream)
{
    const float* src  = (const float*)d_in[0];
    const float* spe  = (const float*)d_in[1];
    const float* rel  = (const float*)d_in[2];
    const float* Wq   = (const float*)d_in[3];
    const float* bq   = (const float*)d_in[4];
    const float* Wk   = (const float*)d_in[5];
    const float* bk   = (const float*)d_in[6];
    const float* Wv   = (const float*)d_in[7];
    const float* bv   = (const float*)d_in[8];
    const float* Wqp  = (const float*)d_in[9];
    const float* bqp  = (const float*)d_in[10];
    const float* Wkp  = (const float*)d_in[11];
    const float* bkp  = (const float*)d_in[12];
    const float* Wvp  = (const float*)d_in[13];
    const float* bvp  = (const float*)d_in[14];
    const float* W1   = (const float*)d_in[15];
    const float* b1   = (const float*)d_in[16];
    const float* W2   = (const float*)d_in[17];
    const float* b2   = (const float*)d_in[18];
    const float* g1   = (const float*)d_in[19];
    const float* be1  = (const float*)d_in[20];
    const float* g2   = (const float*)d_in[21];
    const float* be2  = (const float*)d_in[22];

    float* ws = (float*)d_ws;
    const int NROW = kB * kA;            // 1024
    float* q    = ws;                    // 1024*256
    float* kbuf = ws + 1 * NROW * kD;
    float* qpos = ws + 2 * NROW * kD;
    float* vbuf = ws + 3 * NROW * kD;
    float* xbuf = ws + 4 * NROW * kD;
    float* hbuf = ws + 5 * NROW * kD;    // 1024*2048

    proj3_kernel<<<dim3(128, 3), 256, 0, stream>>>(src, spe, Wq, bq, Wk, bk, Wqp, bqp,
                                                   q, kbuf, qpos);
    projv_kernel<<<dim3(128), 256, 0, stream>>>(kbuf, Wv, bv, vbuf);
    attn_kernel<<<dim3(kA, kB), 256, 0, stream>>>(src, rel, q, qpos, kbuf, vbuf,
                                                  Wkp, bkp, Wvp, bvp, g1, be1, xbuf);
    ffn1_kernel<<<dim3(128, 2), 256, 0, stream>>>(xbuf, W1, b1, hbuf);
    ffn2_ln_kernel<<<dim3(256), 256, 0, stream>>>(xbuf, hbuf, W2, b2, g2, be2,
                                                  (float*)d_out);
}

// Round 2
// 507.960 us; speedup vs baseline: 1.0476x; 1.0476x over previous
//
#include <hip/hip_runtime.h>
#include <math.h>

// Problem constants
#define kB 8
#define kA 128
#define kD 256
#define kF 2048
// hd = 64 (content/pos head dim), vhd = 32, scale = 0.125

// ---------------------------------------------------------------------------
// 16-row x 256-col GEMM: Y[r0+r][t] = sum_c X[r0+r][c]*W[c][t] + b[t]
// ---------------------------------------------------------------------------
__device__ __forceinline__ void gemm16_256(const float* __restrict__ X,
                                           const float* __restrict__ W,
                                           const float* __restrict__ bias,
                                           float* __restrict__ Y,
                                           int r0, int t, float* xs /*16*256*/)
{
    for (int i = 0; i < 16; ++i) xs[i * 256 + t] = X[(r0 + i) * 256 + t];
    __syncthreads();
    float acc[16];
#pragma unroll
    for (int r = 0; r < 16; ++r) acc[r] = 0.f;
    for (int c = 0; c < 256; c += 4) {
        float w0 = W[(c + 0) * 256 + t];
        float w1 = W[(c + 1) * 256 + t];
        float w2 = W[(c + 2) * 256 + t];
        float w3 = W[(c + 3) * 256 + t];
#pragma unroll
        for (int r = 0; r < 16; ++r) {
            float4 xv = *(const float4*)&xs[r * 256 + c];
            acc[r] += xv.x * w0 + xv.y * w1 + xv.z * w2 + xv.w * w3;
        }
    }
    float bv = bias[t];
#pragma unroll
    for (int r = 0; r < 16; ++r) Y[(r0 + r) * 256 + t] = acc[r] + bv;
}

// Kernel 1: q = src@Wq+bq ; k_base = src@Wk+bk ; q_pos = spe@Wqp+bqp
__global__ __launch_bounds__(256) void proj3_kernel(
    const float* __restrict__ src, const float* __restrict__ spe,
    const float* __restrict__ Wq, const float* __restrict__ bq,
    const float* __restrict__ Wk, const float* __restrict__ bk,
    const float* __restrict__ Wqp, const float* __restrict__ bqp,
    float* __restrict__ q, float* __restrict__ kb, float* __restrict__ qpos)
{
    __shared__ float xs[16 * 256];
    const float *X, *W, *B;
    float* Y;
    if (blockIdx.y == 0)      { X = src; W = Wq;  B = bq;  Y = q; }
    else if (blockIdx.y == 1) { X = src; W = Wk;  B = bk;  Y = kb; }
    else                      { X = spe; W = Wqp; B = bqp; Y = qpos; }
    gemm16_256(X, W, B, Y, blockIdx.x * 16, threadIdx.x, xs);
}

// Kernel 2: v_base = k_base@Wv + bv
__global__ __launch_bounds__(256) void projv_kernel(
    const float* __restrict__ kb, const float* __restrict__ Wv,
    const float* __restrict__ bv, float* __restrict__ vb)
{
    __shared__ float xs[16 * 256];
    gemm16_256(kb, Wv, bv, vb, blockIdx.x * 16, threadIdx.x, xs);
}

// ---------------------------------------------------------------------------
// Kernel 3: fused attention + residual + LN1, one block per (b, q) pair.
// ---------------------------------------------------------------------------
__global__ __launch_bounds__(256) void attn_kernel(
    const float* __restrict__ src, const float* __restrict__ rel,
    const float* __restrict__ q, const float* __restrict__ qpos,
    const float* __restrict__ kb, const float* __restrict__ vb,
    const float* __restrict__ Wkp, const float* __restrict__ bkp,
    const float* __restrict__ Wvp, const float* __restrict__ bvp,
    const float* __restrict__ g1, const float* __restrict__ be1,
    float* __restrict__ x_out)
{
    const int t  = threadIdx.x;
    const int qi = blockIdx.x;   // 0..127
    const int b  = blockIdx.y;   // 0..7
    const int row = b * kA + qi;

    __shared__ float q_lds[256];
    __shared__ float qp_lds[256];
    __shared__ float u_lds[4][256];
    __shared__ float beta_lds[4];
    __shared__ float sp_tmp[4][128];
    __shared__ float attn_t[128][8];
    __shared__ float r_lds[8][256];
    __shared__ float redA[4], redB[4];

    q_lds[t]  = q[row * 256 + t];
    qp_lds[t] = qpos[row * 256 + t];
    __syncthreads();

    // ---- Phase 1: u[h][t] over Wkp row t ----
    {
        const float4* wr4 = (const float4*)(Wkp + t * 256);
        const float4* qp4 = (const float4*)qp_lds;
        float acc[4] = {0.f, 0.f, 0.f, 0.f};
#pragma unroll 4
        for (int i = 0; i < 16; ++i) {
#pragma unroll
            for (int hp = 0; hp < 4; ++hp) {
                float4 w  = wr4[hp * 16 + i];
                float4 qv = qp4[hp * 16 + i];
                acc[hp] += qv.x * w.x + qv.y * w.y + qv.z * w.z + qv.w * w.w;
            }
        }
#pragma unroll
        for (int hp = 0; hp < 4; ++hp) u_lds[hp][t] = acc[hp];
        if (t < 4) {
            float s = 0.f;
            for (int e = 0; e < 64; ++e) s += qp_lds[t * 64 + e] * bkp[t * 64 + e];
            beta_lds[t] = s;
        }
    }
    __syncthreads();

    // ---- Phase 2: content scores (heads 0..3) ----
    for (int i = t; i < 512; i += 256) {
        int h = i >> 7, k = i & 127;
        const float4* kr4 = (const float4*)(kb + (b * kA + k) * 256 + h * 64);
        const float4* qr4 = (const float4*)(q_lds + h * 64);
        float s = 0.f;
#pragma unroll
        for (int e = 0; e < 16; ++e) {
            float4 kv = kr4[e], qv = qr4[e];
            s += qv.x * kv.x + qv.y * kv.y + qv.z * kv.z + qv.w * kv.w;
        }
        attn_t[k][h] = s * 0.125f;
    }

    // ---- Phase 3: pos scores (heads 4..7) ----
    {
        int k = t & 127, half = t >> 7;
        const float4* rr4 = (const float4*)(rel + ((size_t)(b * kA + qi) * kA + k) * 256 + half * 128);
        float acc[4] = {0.f, 0.f, 0.f, 0.f};
        for (int i = 0; i < 32; ++i) {
            float4 rv = rr4[i];
            int c4 = half * 32 + i;
#pragma unroll
            for (int hp = 0; hp < 4; ++hp) {
                float4 uv = ((const float4*)u_lds[hp])[c4];
                acc[hp] += rv.x * uv.x + rv.y * uv.y + rv.z * uv.z + rv.w * uv.w;
            }
        }
        if (half == 0) {
#pragma unroll
            for (int hp = 0; hp < 4; ++hp) sp_tmp[hp][k] = acc[hp];
        }
        __syncthreads();
        if (half == 1) {
#pragma unroll
            for (int hp = 0; hp < 4; ++hp)
                attn_t[k][4 + hp] = (sp_tmp[hp][k] + acc[hp] + beta_lds[hp]) * 0.125f;
        }
    }
    __syncthreads();

    // ---- Phase 4: softmax per head ----
    {
        int h = t >> 5, l = t & 31;
        float v0 = attn_t[l][h], v1 = attn_t[l + 32][h];
        float v2 = attn_t[l + 64][h], v3 = attn_t[l + 96][h];
        float m = fmaxf(fmaxf(v0, v1), fmaxf(v2, v3));
#pragma unroll
        for (int sh = 16; sh; sh >>= 1) m = fmaxf(m, __shfl_xor(m, sh, 64));
        v0 = __expf(v0 - m); v1 = __expf(v1 - m);
        v2 = __expf(v2 - m); v3 = __expf(v3 - m);
        float s = v0 + v1 + v2 + v3;
#pragma unroll
        for (int sh = 16; sh; sh >>= 1) s += __shfl_xor(s, sh, 64);
        float inv = 1.0f / s;
        attn_t[l][h] = v0 * inv; attn_t[l + 32][h] = v1 * inv;
        attn_t[l + 64][h] = v2 * inv; attn_t[l + 96][h] = v3 * inv;
    }
    __syncthreads();

    // ---- Phase 5: r[h][c] + content PV ----
    float cacc = 0.f;
    {
        const int ht = t >> 5;
        float racc[8] = {0.f, 0.f, 0.f, 0.f, 0.f, 0.f, 0.f, 0.f};
        const float* relbase = rel + (size_t)(b * kA + qi) * kA * 256 + t;
        const float* vbase   = vb + b * kA * 256 + t;
        for (int k = 0; k < 128; ++k) {
            float rv = relbase[k * 256];
            float vv = vbase[k * 256];
            float4 a0 = *(const float4*)&attn_t[k][0];
            float4 a1 = *(const float4*)&attn_t[k][4];
            racc[0] += a0.x * rv; racc[1] += a0.y * rv;
            racc[2] += a0.z * rv; racc[3] += a0.w * rv;
            racc[4] += a1.x * rv; racc[5] += a1.y * rv;
            racc[6] += a1.z * rv; racc[7] += a1.w * rv;
            cacc += attn_t[k][ht] * vv;
        }
#pragma unroll
        for (int h = 0; h < 8; ++h) r_lds[h][t] = racc[h];
    }
    __syncthreads();

    // ---- Phase 6: pos output = r[h] @ Wvp col t ----
    float out_val;
    {
        const int h = t >> 5;
        const float* wvp = Wvp + t;
        const float4* rrow = (const float4*)r_lds[h];
        float pacc = 0.f;
        for (int c = 0; c < 256; c += 4) {
            float4 r4 = rrow[c >> 2];
            pacc += r4.x * wvp[(c + 0) * 256] + r4.y * wvp[(c + 1) * 256]
                  + r4.z * wvp[(c + 2) * 256] + r4.w * wvp[(c + 3) * 256];
        }
        out_val = cacc + pacc + bvp[t];
    }

    // ---- Phase 7: residual + LayerNorm1 ----
    {
        float y = src[row * 256 + t] + out_val;
        float s1 = y, s2 = y * y;
#pragma unroll
        for (int sh = 32; sh; sh >>= 1) {
            s1 += __shfl_xor(s1, sh, 64);
            s2 += __shfl_xor(s2, sh, 64);
        }
        if ((t & 63) == 0) { redA[t >> 6] = s1; redB[t >> 6] = s2; }
        __syncthreads();
        s1 = redA[0] + redA[1] + redA[2] + redA[3];
        s2 = redB[0] + redB[1] + redB[2] + redB[3];
        float mean = s1 * (1.0f / 256.0f);
        float var  = fmaxf(s2 * (1.0f / 256.0f) - mean * mean, 0.0f);
        float inv  = rsqrtf(var + 1e-5f);
        x_out[row * 256 + t] = (y - mean) * inv * g1[t] + be1[t];
    }
}

// ---------------------------------------------------------------------------
// Kernel 4: fused FFN with K-split over the hidden dim.
// Block = (16 rows, 512-wide hidden chunk). Phase A: h = relu(x@W1c + b1c) in
// LDS. Phase B: part = h @ W2c  -> part[chunk]. Grid (64, 4).
// ---------------------------------------------------------------------------
__global__ __launch_bounds__(256) void ffn_fused_kernel(
    const float* __restrict__ x, const float* __restrict__ W1,
    const float* __restrict__ b1, const float* __restrict__ W2,
    float* __restrict__ part)
{
    __shared__ float xs[16][256];
    __shared__ float hs[16][512];
    const int t  = threadIdx.x;
    const int r0 = blockIdx.x * 16;
    const int c0 = blockIdx.y * 512;

    for (int i = 0; i < 16; ++i) xs[i][t] = x[(r0 + i) * 256 + t];
    __syncthreads();

    // Phase A: 2 hidden cols per thread (t, t+256)
    {
        float accA[16], accB[16];
#pragma unroll
        for (int r = 0; r < 16; ++r) { accA[r] = 0.f; accB[r] = 0.f; }
        for (int k = 0; k < 256; k += 4) {
            float wA[4], wB[4];
#pragma unroll
            for (int j = 0; j < 4; ++j) {
                wA[j] = W1[(k + j) * 2048 + c0 + t];
                wB[j] = W1[(k + j) * 2048 + c0 + 256 + t];
            }
#pragma unroll
            for (int r = 0; r < 16; ++r) {
                float4 xv = *(const float4*)&xs[r][k];
                accA[r] += xv.x * wA[0] + xv.y * wA[1] + xv.z * wA[2] + xv.w * wA[3];
                accB[r] += xv.x * wB[0] + xv.y * wB[1] + xv.z * wB[2] + xv.w * wB[3];
            }
        }
        float bA = b1[c0 + t], bB = b1[c0 + 256 + t];
#pragma unroll
        for (int r = 0; r < 16; ++r) {
            hs[r][t]       = fmaxf(accA[r] + bA, 0.f);
            hs[r][t + 256] = fmaxf(accB[r] + bB, 0.f);
        }
    }
    __syncthreads();

    // Phase B: partial ff over this hidden chunk, output col t
    {
        float acc[16];
#pragma unroll
        for (int r = 0; r < 16; ++r) acc[r] = 0.f;
        for (int k = 0; k < 512; k += 4) {
            float w0 = W2[(c0 + k + 0) * 256 + t];
            float w1 = W2[(c0 + k + 1) * 256 + t];
            float w2 = W2[(c0 + k + 2) * 256 + t];
            float w3 = W2[(c0 + k + 3) * 256 + t];
#pragma unroll
            for (int r = 0; r < 16; ++r) {
                float4 hv = *(const float4*)&hs[r][k];
                acc[r] += hv.x * w0 + hv.y * w1 + hv.z * w2 + hv.w * w3;
            }
        }
#pragma unroll
        for (int r = 0; r < 16; ++r)
            part[((size_t)blockIdx.y * 1024 + r0 + r) * 256 + t] = acc[r];
    }
}

// ---------------------------------------------------------------------------
// Kernel 5: out = LN2(x + sum_chunks part + b2). Block: 4 rows, grid 256.
// ---------------------------------------------------------------------------
__global__ __launch_bounds__(256) void ffn_ln2_kernel(
    const float* __restrict__ x, const float* __restrict__ part,
    const float* __restrict__ b2, const float* __restrict__ g2,
    const float* __restrict__ be2, float* __restrict__ out)
{
    __shared__ float red1[4][4], red2[4][4];
    const int t = threadIdx.x;
    const int r0 = blockIdx.x * 4;
    const int wv = t >> 6, lane = t & 63;
    float b2v = b2[t];
    float yv[4];
#pragma unroll
    for (int r = 0; r < 4; ++r) {
        size_t idx = (size_t)(r0 + r) * 256 + t;
        float y = x[idx] + b2v
                + part[idx] + part[idx + 262144]
                + part[idx + 524288] + part[idx + 786432];
        yv[r] = y;
        float s1 = y, s2 = y * y;
#pragma unroll
        for (int sh = 32; sh; sh >>= 1) {
            s1 += __shfl_xor(s1, sh, 64);
            s2 += __shfl_xor(s2, sh, 64);
        }
        if (lane == 0) { red1[r][wv] = s1; red2[r][wv] = s2; }
    }
    __syncthreads();
    float g = g2[t], be = be2[t];
#pragma unroll
    for (int r = 0; r < 4; ++r) {
        float s1 = red1[r][0] + red1[r][1] + red1[r][2] + red1[r][3];
        float s2 = red2[r][0] + red2[r][1] + red2[r][2] + red2[r][3];
        float mean = s1 * (1.0f / 256.0f);
        float var  = fmaxf(s2 * (1.0f / 256.0f) - mean * mean, 0.0f);
        float inv  = rsqrtf(var + 1e-5f);
        out[(size_t)(r0 + r) * 256 + t] = (yv[r] - mean) * inv * g + be;
    }
}

// ---------------------------------------------------------------------------
extern "C" void kernel_launch(void* const* d_in, const int* in_sizes, int n_in,
                              void* d_out, int out_size, void* d_ws, size_t ws_size,
                              hipStream_t stream)
{
    const float* src  = (const float*)d_in[0];
    const float* spe  = (const float*)d_in[1];
    const float* rel  = (const float*)d_in[2];
    const float* Wq   = (const float*)d_in[3];
    const float* bq   = (const float*)d_in[4];
    const float* Wk   = (const float*)d_in[5];
    const float* bk   = (const float*)d_in[6];
    const float* Wv   = (const float*)d_in[7];
    const float* bv   = (const float*)d_in[8];
    const float* Wqp  = (const float*)d_in[9];
    const float* bqp  = (const float*)d_in[10];
    const float* Wkp  = (const float*)d_in[11];
    const float* bkp  = (const float*)d_in[12];
    const float* Wvp  = (const float*)d_in[13];
    const float* bvp  = (const float*)d_in[14];
    const float* W1   = (const float*)d_in[15];
    const float* b1   = (const float*)d_in[16];
    const float* W2   = (const float*)d_in[17];
    const float* b2   = (const float*)d_in[18];
    const float* g1   = (const float*)d_in[19];
    const float* be1  = (const float*)d_in[20];
    const float* g2   = (const float*)d_in[21];
    const float* be2  = (const float*)d_in[22];

    float* ws = (float*)d_ws;
    const int NROW = kB * kA;            // 1024
    float* q    = ws;                    // 1024*256 each
    float* kbuf = ws + 1 * NROW * kD;
    float* qpos = ws + 2 * NROW * kD;
    float* vbuf = ws + 3 * NROW * kD;
    float* xbuf = ws + 4 * NROW * kD;
    // part reuses [0 .. 4*NROW*kD): q/kbuf/qpos/vbuf are dead after attn.
    float* part = ws;

    proj3_kernel<<<dim3(64, 3), 256, 0, stream>>>(src, spe, Wq, bq, Wk, bk, Wqp, bqp,
                                                  q, kbuf, qpos);
    projv_kernel<<<dim3(64), 256, 0, stream>>>(kbuf, Wv, bv, vbuf);
    attn_kernel<<<dim3(kA, kB), 256, 0, stream>>>(src, rel, q, qpos, kbuf, vbuf,
                                                  Wkp, bkp, Wvp, bvp, g1, be1, xbuf);
    ffn_fused_kernel<<<dim3(64, 4), 256, 0, stream>>>(xbuf, W1, b1, W2, part);
    ffn_ln2_kernel<<<dim3(256), 256, 0, stream>>>(xbuf, part, b2, g2, be2,
                                                  (float*)d_out);
}

// Round 3
// 429.154 us; speedup vs baseline: 1.2400x; 1.1836x over previous
//
#include <hip/hip_runtime.h>
#include <math.h>

// Problem constants
#define kB 8
#define kA 128
#define kD 256
#define kF 2048
// hd = 64 (content/pos head dim), vhd = 32, scale = 0.125

#define NROW (kB * kA)          // 1024
#define ST_PITCH 264            // stage row pitch in floats (66 float4)
#define AT_PITCH 12             // attn_t row pitch in floats (16B-aligned float4)

// ---------------------------------------------------------------------------
// 8-row x 256-col GEMM: Y[r0+r][t] = sum_c X[r0+r][c]*W[c][t] + b[t]
// ---------------------------------------------------------------------------
__device__ __forceinline__ void gemm8_256(const float* __restrict__ X,
                                          const float* __restrict__ W,
                                          const float* __restrict__ bias,
                                          float* __restrict__ Y,
                                          int r0, int t, float* xs /*8*256*/)
{
    for (int i = 0; i < 8; ++i) xs[i * 256 + t] = X[(r0 + i) * 256 + t];
    __syncthreads();
    float acc[8] = {0.f, 0.f, 0.f, 0.f, 0.f, 0.f, 0.f, 0.f};
    for (int c = 0; c < 256; c += 4) {
        float w0 = W[(c + 0) * 256 + t];
        float w1 = W[(c + 1) * 256 + t];
        float w2 = W[(c + 2) * 256 + t];
        float w3 = W[(c + 3) * 256 + t];
#pragma unroll
        for (int r = 0; r < 8; ++r) {
            float4 xv = *(const float4*)&xs[r * 256 + c];
            acc[r] += xv.x * w0 + xv.y * w1 + xv.z * w2 + xv.w * w3;
        }
    }
    float bv = bias[t];
#pragma unroll
    for (int r = 0; r < 8; ++r) Y[(r0 + r) * 256 + t] = acc[r] + bv;
}

// Kernel 1: q = src@Wq+bq ; k_base = src@Wk+bk ; q_pos = spe@Wqp+bqp
__global__ __launch_bounds__(256) void proj3_kernel(
    const float* __restrict__ src, const float* __restrict__ spe,
    const float* __restrict__ Wq, const float* __restrict__ bq,
    const float* __restrict__ Wk, const float* __restrict__ bk,
    const float* __restrict__ Wqp, const float* __restrict__ bqp,
    float* __restrict__ q, float* __restrict__ kb, float* __restrict__ qpos)
{
    __shared__ float xs[8 * 256];
    const float *X, *W, *B;
    float* Y;
    if (blockIdx.y == 0)      { X = src; W = Wq;  B = bq;  Y = q; }
    else if (blockIdx.y == 1) { X = src; W = Wk;  B = bk;  Y = kb; }
    else                      { X = spe; W = Wqp; B = bqp; Y = qpos; }
    gemm8_256(X, W, B, Y, blockIdx.x * 8, threadIdx.x, xs);
}

// Kernel 2: v_base = k_base@Wv + bv
__global__ __launch_bounds__(256) void projv_kernel(
    const float* __restrict__ kb, const float* __restrict__ Wv,
    const float* __restrict__ bv, float* __restrict__ vb)
{
    __shared__ float xs[8 * 256];
    gemm8_256(kb, Wv, bv, vb, blockIdx.x * 8, threadIdx.x, xs);
}

// ---------------------------------------------------------------------------
// Kernel 3: fused attention + residual + LN1, one block per (b, q) pair.
// Row-streaming phases: each wave stages 4 full 256-float rows into its own
// LDS buffer with coalesced float4 wave-loads (1 row per wave-load), then
// computes dots from LDS with shuffle reduction. No block barrier inside the
// streaming loops (wave-private buffers, per-wave in-order LDS).
// ---------------------------------------------------------------------------
__global__ __launch_bounds__(256) void attn_kernel(
    const float* __restrict__ src, const float* __restrict__ rel,
    const float* __restrict__ q, const float* __restrict__ qpos,
    const float* __restrict__ kb, const float* __restrict__ vb,
    const float* __restrict__ Wkp, const float* __restrict__ bkp,
    const float* __restrict__ Wvp, const float* __restrict__ bvp,
    const float* __restrict__ g1, const float* __restrict__ be1,
    float* __restrict__ x_out)
{
    const int t  = threadIdx.x;
    const int w  = t >> 6;       // wave 0..3
    const int l  = t & 63;       // lane
    const int r  = l >> 4;       // row-in-group 0..3
    const int p  = l & 15;       // 16-lane part
    const int qi = blockIdx.x;   // 0..127
    const int b  = blockIdx.y;   // 0..7
    const int row = b * kA + qi;

    __shared__ float q_lds[256];
    __shared__ float qp_lds[256];
    __shared__ float u_lds[4][ST_PITCH];
    __shared__ float stage[4][4 * ST_PITCH];   // per-wave 4-row buffer
    __shared__ float attn_t[128][AT_PITCH];
    __shared__ float beta_lds[4];
    __shared__ float r_lds[8][256];
    __shared__ float redA[4], redB[4];

    q_lds[t]  = q[(size_t)row * 256 + t];
    qp_lds[t] = qpos[(size_t)row * 256 + t];
    __syncthreads();   // B0

    // ---- Phase 1: u[h][c] = dot(qp_h, Wkp[c] head-slice). Wave w: rows [64w,64w+64).
    {
        float* st = stage[w];
        float4* st4 = (float4*)st;
        const float* Wbase = Wkp + (size_t)(w * 64) * 256;
        const int h = p >> 2;
        const float* qrow = qp_lds + h * 64 + (p & 3);
        for (int g = 0; g < 16; ++g) {
#pragma unroll
            for (int i = 0; i < 4; ++i)
                st4[i * 66 + l] = ((const float4*)(Wbase + (g * 4 + i) * 256))[l];
            asm volatile("" ::: "memory");
            const float* srow = st + r * ST_PITCH + h * 64 + (p & 3);
            float acc = 0.f;
#pragma unroll
            for (int j = 0; j < 16; ++j) acc += srow[4 * j] * qrow[4 * j];
            acc += __shfl_xor(acc, 1, 64);
            acc += __shfl_xor(acc, 2, 64);
            if ((p & 3) == 0) u_lds[h][w * 64 + g * 4 + r] = acc;
            asm volatile("" ::: "memory");
        }
        if (t < 4) {   // beta[h] = qp_h . bkp_h
            float s = 0.f;
            for (int e = 0; e < 64; ++e) s += qp_lds[t * 64 + e] * bkp[t * 64 + e];
            beta_lds[t] = s;
        }
    }
    __syncthreads();   // B1

    // ---- Phase 2: content scores s_con[h,k] (heads 0..3). Wave w: k in [32w,32w+32).
    {
        float* st = stage[w];
        float4* st4 = (float4*)st;
        const float* Kbase = kb + ((size_t)b * kA + w * 32) * 256;
        const int h = p >> 2;
        const float* qrow = q_lds + h * 64 + (p & 3);
        for (int g = 0; g < 8; ++g) {
#pragma unroll
            for (int i = 0; i < 4; ++i)
                st4[i * 66 + l] = ((const float4*)(Kbase + (g * 4 + i) * 256))[l];
            asm volatile("" ::: "memory");
            const float* srow = st + r * ST_PITCH + h * 64 + (p & 3);
            float acc = 0.f;
#pragma unroll
            for (int j = 0; j < 16; ++j) acc += srow[4 * j] * qrow[4 * j];
            acc += __shfl_xor(acc, 1, 64);
            acc += __shfl_xor(acc, 2, 64);
            if ((p & 3) == 0) attn_t[w * 32 + g * 4 + r][h] = acc * 0.125f;
            asm volatile("" ::: "memory");
        }
    }

    // ---- Phase 3: pos scores s_pos[h,k] (heads 4..7): dot(rel[k], u[h]) over 256.
    {
        float* st = stage[w];
        float4* st4 = (float4*)st;
        const float* Rbase = rel + ((size_t)row * kA + w * 32) * 256;
        for (int g = 0; g < 8; ++g) {
#pragma unroll
            for (int i = 0; i < 4; ++i)
                st4[i * 66 + l] = ((const float4*)(Rbase + (g * 4 + i) * 256))[l];
            asm volatile("" ::: "memory");
            const float* srow = st + r * ST_PITCH + p;
            float a0 = 0.f, a1 = 0.f, a2 = 0.f, a3 = 0.f;
#pragma unroll
            for (int j = 0; j < 16; ++j) {
                float sv = srow[16 * j];
                a0 += sv * u_lds[0][p + 16 * j];
                a1 += sv * u_lds[1][p + 16 * j];
                a2 += sv * u_lds[2][p + 16 * j];
                a3 += sv * u_lds[3][p + 16 * j];
            }
#pragma unroll
            for (int sh = 1; sh < 16; sh <<= 1) {
                a0 += __shfl_xor(a0, sh, 64);
                a1 += __shfl_xor(a1, sh, 64);
                a2 += __shfl_xor(a2, sh, 64);
                a3 += __shfl_xor(a3, sh, 64);
            }
            if (p < 4) {
                float av = (p == 0) ? a0 : (p == 1) ? a1 : (p == 2) ? a2 : a3;
                attn_t[w * 32 + g * 4 + r][4 + p] = (av + beta_lds[p]) * 0.125f;
            }
            asm volatile("" ::: "memory");
        }
    }
    __syncthreads();   // B2

    // ---- Phase 4: softmax per head over k ----
    {
        int h = t >> 5, l32 = t & 31;
        float v0 = attn_t[l32][h], v1 = attn_t[l32 + 32][h];
        float v2 = attn_t[l32 + 64][h], v3 = attn_t[l32 + 96][h];
        float m = fmaxf(fmaxf(v0, v1), fmaxf(v2, v3));
#pragma unroll
        for (int sh = 16; sh; sh >>= 1) m = fmaxf(m, __shfl_xor(m, sh, 64));
        v0 = __expf(v0 - m); v1 = __expf(v1 - m);
        v2 = __expf(v2 - m); v3 = __expf(v3 - m);
        float s = v0 + v1 + v2 + v3;
#pragma unroll
        for (int sh = 16; sh; sh >>= 1) s += __shfl_xor(s, sh, 64);
        float inv = 1.0f / s;
        attn_t[l32][h] = v0 * inv; attn_t[l32 + 32][h] = v1 * inv;
        attn_t[l32 + 64][h] = v2 * inv; attn_t[l32 + 96][h] = v3 * inv;
    }
    __syncthreads();   // B3

    // ---- Phase 5: r[h][c] = sum_k attn[h,k]*rel[k,c]  and content PV ----
    float cacc = 0.f;
    {
        const int ht = t >> 5;
        float racc[8] = {0.f, 0.f, 0.f, 0.f, 0.f, 0.f, 0.f, 0.f};
        const float* relbase = rel + (size_t)row * kA * 256 + t;
        const float* vbase   = vb + (size_t)b * kA * 256 + t;
#pragma unroll 4
        for (int k = 0; k < 128; ++k) {
            float rv = relbase[(size_t)k * 256];
            float vv = vbase[(size_t)k * 256];
            float4 a0 = *(const float4*)&attn_t[k][0];
            float4 a1 = *(const float4*)&attn_t[k][4];
            racc[0] += a0.x * rv; racc[1] += a0.y * rv;
            racc[2] += a0.z * rv; racc[3] += a0.w * rv;
            racc[4] += a1.x * rv; racc[5] += a1.y * rv;
            racc[6] += a1.z * rv; racc[7] += a1.w * rv;
            float av = (ht < 4) ? ((ht == 0) ? a0.x : (ht == 1) ? a0.y : (ht == 2) ? a0.z : a0.w)
                                : ((ht == 4) ? a1.x : (ht == 5) ? a1.y : (ht == 6) ? a1.z : a1.w);
            cacc += av * vv;
        }
#pragma unroll
        for (int h = 0; h < 8; ++h) r_lds[h][t] = racc[h];
    }
    __syncthreads();   // B4

    // ---- Phase 6: pos output = r[h] @ Wvp col t, + bvp ----
    float out_val;
    {
        const int h = t >> 5;
        const float* wvp = Wvp + t;
        const float4* rrow = (const float4*)r_lds[h];
        float pacc = 0.f;
        for (int c = 0; c < 256; c += 4) {
            float4 r4 = rrow[c >> 2];
            pacc += r4.x * wvp[(c + 0) * 256] + r4.y * wvp[(c + 1) * 256]
                  + r4.z * wvp[(c + 2) * 256] + r4.w * wvp[(c + 3) * 256];
        }
        out_val = cacc + pacc + bvp[t];
    }

    // ---- Phase 7: residual + LayerNorm1 ----
    {
        float y = src[(size_t)row * 256 + t] + out_val;
        float s1 = y, s2 = y * y;
#pragma unroll
        for (int sh = 32; sh; sh >>= 1) {
            s1 += __shfl_xor(s1, sh, 64);
            s2 += __shfl_xor(s2, sh, 64);
        }
        if ((t & 63) == 0) { redA[t >> 6] = s1; redB[t >> 6] = s2; }
        __syncthreads();   // B5
        s1 = redA[0] + redA[1] + redA[2] + redA[3];
        s2 = redB[0] + redB[1] + redB[2] + redB[3];
        float mean = s1 * (1.0f / 256.0f);
        float var  = fmaxf(s2 * (1.0f / 256.0f) - mean * mean, 0.0f);
        float inv  = rsqrtf(var + 1e-5f);
        x_out[(size_t)row * 256 + t] = (y - mean) * inv * g1[t] + be1[t];
    }
}

// ---------------------------------------------------------------------------
// Kernel 4: fused FFN, K-split over hidden. Block = 8 rows x 512 hidden chunk.
// Grid (128, 4) = 512 blocks. part[chunk] = h_chunk @ W2_chunk.
// ---------------------------------------------------------------------------
__global__ __launch_bounds__(256) void ffn_fused_kernel(
    const float* __restrict__ x, const float* __restrict__ W1,
    const float* __restrict__ b1, const float* __restrict__ W2,
    float* __restrict__ part)
{
    __shared__ float xs[8][260];
    __shared__ float hs[8][520];
    const int t  = threadIdx.x;
    const int r0 = blockIdx.x * 8;
    const int c0 = blockIdx.y * 512;

#pragma unroll
    for (int i = 0; i < 8; ++i) xs[i][t] = x[(size_t)(r0 + i) * 256 + t];
    __syncthreads();

    // Phase A: h = relu(x @ W1[:, c0 + {t, t+256}])
    {
        float accA[8], accB[8];
#pragma unroll
        for (int rr = 0; rr < 8; ++rr) { accA[rr] = 0.f; accB[rr] = 0.f; }
        for (int k = 0; k < 256; k += 4) {
            float wA[4], wB[4];
#pragma unroll
            for (int j = 0; j < 4; ++j) {
                wA[j] = W1[(size_t)(k + j) * 2048 + c0 + t];
                wB[j] = W1[(size_t)(k + j) * 2048 + c0 + 256 + t];
            }
#pragma unroll
            for (int rr = 0; rr < 8; ++rr) {
                float4 xv = *(const float4*)&xs[rr][k];
                accA[rr] += xv.x * wA[0] + xv.y * wA[1] + xv.z * wA[2] + xv.w * wA[3];
                accB[rr] += xv.x * wB[0] + xv.y * wB[1] + xv.z * wB[2] + xv.w * wB[3];
            }
        }
        float bA = b1[c0 + t], bB = b1[c0 + 256 + t];
#pragma unroll
        for (int rr = 0; rr < 8; ++rr) {
            hs[rr][t]       = fmaxf(accA[rr] + bA, 0.f);
            hs[rr][t + 256] = fmaxf(accB[rr] + bB, 0.f);
        }
    }
    __syncthreads();

    // Phase B: part = h @ W2[c0:c0+512, t]
    {
        float acc[8];
#pragma unroll
        for (int rr = 0; rr < 8; ++rr) acc[rr] = 0.f;
        for (int k = 0; k < 512; k += 4) {
            float w0 = W2[(size_t)(c0 + k + 0) * 256 + t];
            float w1 = W2[(size_t)(c0 + k + 1) * 256 + t];
            float w2 = W2[(size_t)(c0 + k + 2) * 256 + t];
            float w3 = W2[(size_t)(c0 + k + 3) * 256 + t];
#pragma unroll
            for (int rr = 0; rr < 8; ++rr) {
                float4 hv = *(const float4*)&hs[rr][k];
                acc[rr] += hv.x * w0 + hv.y * w1 + hv.z * w2 + hv.w * w3;
            }
        }
#pragma unroll
        for (int rr = 0; rr < 8; ++rr)
            part[((size_t)blockIdx.y * NROW + r0 + rr) * 256 + t] = acc[rr];
    }
}

// ---------------------------------------------------------------------------
// Kernel 5: out = LN2(x + sum_chunks part + b2). Block: 4 rows, grid 256.
// ---------------------------------------------------------------------------
__global__ __launch_bounds__(256) void ffn_ln2_kernel(
    const float* __restrict__ x, const float* __restrict__ part,
    const float* __restrict__ b2, const float* __restrict__ g2,
    const float* __restrict__ be2, float* __restrict__ out)
{
    __shared__ float red1[4][4], red2[4][4];
    const int t = threadIdx.x;
    const int r0 = blockIdx.x * 4;
    const int wv = t >> 6, lane = t & 63;
    float b2v = b2[t];
    float yv[4];
#pragma unroll
    for (int r = 0; r < 4; ++r) {
        size_t idx = (size_t)(r0 + r) * 256 + t;
        float y = x[idx] + b2v;
#pragma unroll
        for (int c = 0; c < 4; ++c) y += part[idx + (size_t)c * (NROW * 256)];
        yv[r] = y;
        float s1 = y, s2 = y * y;
#pragma unroll
        for (int sh = 32; sh; sh >>= 1) {
            s1 += __shfl_xor(s1, sh, 64);
            s2 += __shfl_xor(s2, sh, 64);
        }
        if (lane == 0) { red1[r][wv] = s1; red2[r][wv] = s2; }
    }
    __syncthreads();
    float g = g2[t], be = be2[t];
#pragma unroll
    for (int r = 0; r < 4; ++r) {
        float s1 = red1[r][0] + red1[r][1] + red1[r][2] + red1[r][3];
        float s2 = red2[r][0] + red2[r][1] + red2[r][2] + red2[r][3];
        float mean = s1 * (1.0f / 256.0f);
        float var  = fmaxf(s2 * (1.0f / 256.0f) - mean * mean, 0.0f);
        float inv  = rsqrtf(var + 1e-5f);
        out[(size_t)(r0 + r) * 256 + t] = (yv[r] - mean) * inv * g + be;
    }
}

// ---------------------------------------------------------------------------
extern "C" void kernel_launch(void* const* d_in, const int* in_sizes, int n_in,
                              void* d_out, int out_size, void* d_ws, size_t ws_size,
                              hipStream_t stream)
{
    const float* src  = (const float*)d_in[0];
    const float* spe  = (const float*)d_in[1];
    const float* rel  = (const float*)d_in[2];
    const float* Wq   = (const float*)d_in[3];
    const float* bq   = (const float*)d_in[4];
    const float* Wk   = (const float*)d_in[5];
    const float* bk   = (const float*)d_in[6];
    const float* Wv   = (const float*)d_in[7];
    const float* bv   = (const float*)d_in[8];
    const float* Wqp  = (const float*)d_in[9];
    const float* bqp  = (const float*)d_in[10];
    const float* Wkp  = (const float*)d_in[11];
    const float* bkp  = (const float*)d_in[12];
    const float* Wvp  = (const float*)d_in[13];
    const float* bvp  = (const float*)d_in[14];
    const float* W1   = (const float*)d_in[15];
    const float* b1   = (const float*)d_in[16];
    const float* W2   = (const float*)d_in[17];
    const float* b2   = (const float*)d_in[18];
    const float* g1   = (const float*)d_in[19];
    const float* be1  = (const float*)d_in[20];
    const float* g2   = (const float*)d_in[21];
    const float* be2  = (const float*)d_in[22];

    float* ws = (float*)d_ws;
    float* q    = ws;                    // 1024*256 each
    float* kbuf = ws + 1 * NROW * kD;
    float* qpos = ws + 2 * NROW * kD;
    float* vbuf = ws + 3 * NROW * kD;
    float* xbuf = ws + 4 * NROW * kD;
    float* part = ws + 5 * NROW * kD;    // 4 chunks x 1 MB

    proj3_kernel<<<dim3(128, 3), 256, 0, stream>>>(src, spe, Wq, bq, Wk, bk, Wqp, bqp,
                                                   q, kbuf, qpos);
    projv_kernel<<<dim3(128), 256, 0, stream>>>(kbuf, Wv, bv, vbuf);
    attn_kernel<<<dim3(kA, kB), 256, 0, stream>>>(src, rel, q, qpos, kbuf, vbuf,
                                                  Wkp, bkp, Wvp, bvp, g1, be1, xbuf);
    ffn_fused_kernel<<<dim3(128, 4), 256, 0, stream>>>(xbuf, W1, b1, W2, part);
    ffn_ln2_kernel<<<dim3(256), 256, 0, stream>>>(xbuf, part, b2, g2, be2,
                                                  (float*)d_out);
}

// Round 4
// 351.943 us; speedup vs baseline: 1.5120x; 1.2194x over previous
//
#include <hip/hip_runtime.h>
#include <hip/hip_bf16.h>
#include <math.h>

#define kB 8
#define kA 128
#define kD 256
#define kF 2048
#define NROW 1024

typedef __attribute__((ext_vector_type(8))) __bf16 bf16x8;
typedef __attribute__((ext_vector_type(4))) __bf16 bf16x4;
typedef __attribute__((ext_vector_type(4))) float f32x4;

#define MFMA16(a, b, c) __builtin_amdgcn_mfma_f32_16x16x32_bf16(a, b, c, 0, 0, 0)

// Fragment loaders. Both A and B fragments of mfma_f32_16x16x32_bf16 use the
// same per-lane address pattern on a row-major source with the contraction
// dim contiguous: base + (lane&15)*pitch + (lane>>4)*8.
// A: row m = lane&15, k = (lane>>4)*8 + j.  B: col n = lane&15, k likewise.
// C/D: col n = lane&15, row m = (lane>>4)*4 + i.  [verified layouts, m89/m101]
__device__ __forceinline__ bf16x8 frag_f32(const float* p) {
    float4 a = *(const float4*)p;
    float4 b = *(const float4*)(p + 4);
    bf16x8 v;
    v[0] = (__bf16)a.x; v[1] = (__bf16)a.y; v[2] = (__bf16)a.z; v[3] = (__bf16)a.w;
    v[4] = (__bf16)b.x; v[5] = (__bf16)b.y; v[6] = (__bf16)b.z; v[7] = (__bf16)b.w;
    return v;
}
__device__ __forceinline__ bf16x8 frag_bf16(const __bf16* p) {
    return *(const bf16x8*)p;
}

// ---------------------------------------------------------------------------
// Prep: transpose + cvt weights to bf16: out[C][R] = (bf16) in[R][C].
// Segments: 5x (256x256): Wq,Wk,Wqp,Wv,Wvp (16 tiles each = 80),
// W1 (256x2048, 128 tiles), W2 (2048x256, 128 tiles). Total 336 blocks.
// ---------------------------------------------------------------------------
__global__ __launch_bounds__(256) void prep_transpose_kernel(
    const float* __restrict__ Wq, const float* __restrict__ Wk,
    const float* __restrict__ Wqp, const float* __restrict__ Wv,
    const float* __restrict__ Wvp, const float* __restrict__ W1,
    const float* __restrict__ W2,
    __bf16* WqT, __bf16* WkT, __bf16* WqpT, __bf16* WvT, __bf16* WvpT,
    __bf16* W1T, __bf16* W2T)
{
    int bid = blockIdx.x;
    const float* in; __bf16* out; int R, C;
    if (bid < 80) {
        int m = bid >> 4; bid &= 15;
        const float* ins[5] = {Wq, Wk, Wqp, Wv, Wvp};
        __bf16* outs[5] = {WqT, WkT, WqpT, WvT, WvpT};
        in = ins[m]; out = outs[m]; R = 256; C = 256;
    } else if (bid < 208) { bid -= 80; in = W1; out = W1T; R = 256; C = 2048; }
    else { bid -= 208; in = W2; out = W2T; R = 2048; C = 256; }
    int tilesC = C >> 6;
    int r0 = (bid / tilesC) << 6, c0 = (bid % tilesC) << 6;
    __shared__ float tile[64][65];
    int t = threadIdx.x, tr = t >> 6, tc = t & 63;
#pragma unroll
    for (int i = 0; i < 16; ++i)
        tile[tr + i * 4][tc] = in[(size_t)(r0 + tr + i * 4) * C + c0 + tc];
    __syncthreads();
#pragma unroll
    for (int i = 0; i < 16; ++i) {
        int oc = tr + i * 4;   // original col index within tile
        out[(size_t)(c0 + oc) * R + r0 + tc] = (__bf16)tile[tc][oc];
    }
}

// ---------------------------------------------------------------------------
// proj3: q = src@Wq+bq ; kb = src@Wk+bk ; qpos = spe@Wqp+bqp (fp32 out)
// grid (16 m-blocks of 64 rows, 4 n-blocks of 64 cols, 3 mats)
// ---------------------------------------------------------------------------
__global__ __launch_bounds__(256) void proj3_mfma(
    const float* __restrict__ src, const float* __restrict__ spe,
    const __bf16* __restrict__ WqT, const __bf16* __restrict__ WkT,
    const __bf16* __restrict__ WqpT,
    const float* __restrict__ bq, const float* __restrict__ bk,
    const float* __restrict__ bqp,
    float* __restrict__ q, float* __restrict__ kb, float* __restrict__ qpos)
{
    const float* X; const __bf16* WT; const float* bias; float* Y;
    if (blockIdx.z == 0)      { X = src; WT = WqT;  bias = bq;  Y = q; }
    else if (blockIdx.z == 1) { X = src; WT = WkT;  bias = bk;  Y = kb; }
    else                      { X = spe; WT = WqpT; bias = bqp; Y = qpos; }
    int t = threadIdx.x, w = t >> 6, l = t & 63;
    int p = l & 15, g = l >> 4;
    int m0 = blockIdx.x * 64 + w * 16;
    int n0 = blockIdx.y * 64;
    f32x4 acc[4] = {{0.f,0.f,0.f,0.f},{0.f,0.f,0.f,0.f},{0.f,0.f,0.f,0.f},{0.f,0.f,0.f,0.f}};
#pragma unroll
    for (int ks = 0; ks < 8; ++ks) {
        bf16x8 a = frag_f32(X + (size_t)(m0 + p) * 256 + ks * 32 + g * 8);
#pragma unroll
        for (int nt = 0; nt < 4; ++nt) {
            bf16x8 bb = frag_bf16(WT + (size_t)(n0 + nt * 16 + p) * 256 + ks * 32 + g * 8);
            acc[nt] = MFMA16(a, bb, acc[nt]);
        }
    }
#pragma unroll
    for (int nt = 0; nt < 4; ++nt) {
        int col = n0 + nt * 16 + p;
        float bv = bias[col];
#pragma unroll
        for (int i = 0; i < 4; ++i)
            Y[(size_t)(m0 + g * 4 + i) * 256 + col] = acc[nt][i] + bv;
    }
}

// ---------------------------------------------------------------------------
// projv: vb = kb@Wv + bv, stored TRANSPOSED bf16: vbT[b][e][k]
// grid (16, 4)
// ---------------------------------------------------------------------------
__global__ __launch_bounds__(256) void projv_mfma(
    const float* __restrict__ kb, const __bf16* __restrict__ WvT,
    const float* __restrict__ bv, __bf16* __restrict__ vbT)
{
    int t = threadIdx.x, w = t >> 6, l = t & 63;
    int p = l & 15, g = l >> 4;
    int m0 = blockIdx.x * 64 + w * 16;
    int n0 = blockIdx.y * 64;
    f32x4 acc[4] = {{0.f,0.f,0.f,0.f},{0.f,0.f,0.f,0.f},{0.f,0.f,0.f,0.f},{0.f,0.f,0.f,0.f}};
#pragma unroll
    for (int ks = 0; ks < 8; ++ks) {
        bf16x8 a = frag_f32(kb + (size_t)(m0 + p) * 256 + ks * 32 + g * 8);
#pragma unroll
        for (int nt = 0; nt < 4; ++nt) {
            bf16x8 bb = frag_bf16(WvT + (size_t)(n0 + nt * 16 + p) * 256 + ks * 32 + g * 8);
            acc[nt] = MFMA16(a, bb, acc[nt]);
        }
    }
#pragma unroll
    for (int nt = 0; nt < 4; ++nt) {
        int e = n0 + nt * 16 + p;
        float bvv = bv[e];
#pragma unroll
        for (int i = 0; i < 4; ++i) {
            int row = m0 + g * 4 + i;        // global token index
            vbT[((size_t)(row >> 7) * 256 + e) * 128 + (row & 127)] =
                (__bf16)(acc[nt][i] + bvv);
        }
    }
}

// ---------------------------------------------------------------------------
// u: u[bq][h][c] = sum_e qpos[bq][h*64+e] * Wkp[c][h*64+e]  (bf16 out)
// grid (64 m-tiles of 16 rows, 4 heads)
// ---------------------------------------------------------------------------
__global__ __launch_bounds__(256) void u_mfma(
    const float* __restrict__ qpos, const float* __restrict__ Wkp,
    __bf16* __restrict__ u_buf)
{
    int t = threadIdx.x, w = t >> 6, l = t & 63;
    int p = l & 15, g = l >> 4;
    int m0 = blockIdx.x * 16;
    int h = blockIdx.y;
    f32x4 acc[4] = {{0.f,0.f,0.f,0.f},{0.f,0.f,0.f,0.f},{0.f,0.f,0.f,0.f},{0.f,0.f,0.f,0.f}};
#pragma unroll
    for (int ks = 0; ks < 2; ++ks) {
        bf16x8 a = frag_f32(qpos + (size_t)(m0 + p) * 256 + h * 64 + ks * 32 + g * 8);
#pragma unroll
        for (int nt = 0; nt < 4; ++nt) {
            int c0 = w * 64 + nt * 16;
            bf16x8 bb = frag_f32(Wkp + (size_t)(c0 + p) * 256 + h * 64 + ks * 32 + g * 8);
            acc[nt] = MFMA16(a, bb, acc[nt]);
        }
    }
#pragma unroll
    for (int nt = 0; nt < 4; ++nt) {
        int c = w * 64 + nt * 16 + p;
#pragma unroll
        for (int i = 0; i < 4; ++i)
            u_buf[((size_t)(m0 + g * 4 + i) * 4 + h) * 256 + c] = (__bf16)acc[nt][i];
    }
}

// ---------------------------------------------------------------------------
// content scores: s_con[b][h][q][k] = q_h . kb_h  (raw, unscaled, fp32)
// grid (8 b, 4 h)
// ---------------------------------------------------------------------------
__global__ __launch_bounds__(256) void con_mfma(
    const float* __restrict__ q, const float* __restrict__ kb,
    float* __restrict__ s_con)
{
    int t = threadIdx.x, w = t >> 6, l = t & 63;
    int p = l & 15, g = l >> 4;
    int b = blockIdx.x, h = blockIdx.y;
    f32x4 acc[2][8];
#pragma unroll
    for (int mm = 0; mm < 2; ++mm)
#pragma unroll
        for (int nt = 0; nt < 8; ++nt) acc[mm][nt] = (f32x4){0.f,0.f,0.f,0.f};
#pragma unroll
    for (int ks = 0; ks < 2; ++ks) {
        bf16x8 a0 = frag_f32(q + (size_t)(b * 128 + w * 32 + p) * 256 + h * 64 + ks * 32 + g * 8);
        bf16x8 a1 = frag_f32(q + (size_t)(b * 128 + w * 32 + 16 + p) * 256 + h * 64 + ks * 32 + g * 8);
#pragma unroll
        for (int nt = 0; nt < 8; ++nt) {
            bf16x8 bb = frag_f32(kb + (size_t)(b * 128 + nt * 16 + p) * 256 + h * 64 + ks * 32 + g * 8);
            acc[0][nt] = MFMA16(a0, bb, acc[0][nt]);
            acc[1][nt] = MFMA16(a1, bb, acc[1][nt]);
        }
    }
    float* out = s_con + (size_t)(b * 4 + h) * 16384;
#pragma unroll
    for (int mm = 0; mm < 2; ++mm)
#pragma unroll
        for (int nt = 0; nt < 8; ++nt)
#pragma unroll
            for (int i = 0; i < 4; ++i)
                out[(size_t)(w * 32 + mm * 16 + g * 4 + i) * 128 + nt * 16 + p] = acc[mm][nt][i];
}

// ---------------------------------------------------------------------------
// Fused attention, MFMA. One block per (b, q). 256 thr, 2 blocks/CU.
// Pass 1 (per wave, k-rows 32w..32w+31, shared R frags):
//   S_pos^T(16h x 128k) = U^T . R^T      (contract over c)
//   G(128k x 256e)      = R . Wvp        (contract over c)  -> Gt swizzled LDS
// softmax over concat(content, pos) scores
// Pass 2: O(16h x 256e) = A . VbT-frags + A . Gt-frags  (contract over k)
// epilogue: +bvp +src, LayerNorm1.
// ---------------------------------------------------------------------------
__global__ __launch_bounds__(256, 2) void attn_mfma(
    const float* __restrict__ src, const float* __restrict__ rel,
    const __bf16* __restrict__ u_buf, const float* __restrict__ s_con,
    const __bf16* __restrict__ vbT, const __bf16* __restrict__ WvpT,
    const float* __restrict__ qpos, const float* __restrict__ bkp,
    const float* __restrict__ bvp, const float* __restrict__ g1,
    const float* __restrict__ be1, float* __restrict__ x_out)
{
    const int t = threadIdx.x, w = t >> 6, l = t & 63;
    const int p = l & 15, g = l >> 4;
    const int qi = blockIdx.x, b = blockIdx.y;
    const int row = b * 128 + qi;

    __shared__ __bf16 Gt[256 * 128];       // [e][k], k-blocks-of-8 XOR-swizzled by (e&7)
    __shared__ __bf16 A_lds[16 * 136];     // [h][k], pitch 136
    __shared__ float s_lds[128][9];        // [k][h], pitch 9
    __shared__ float out_lds[256];
    __shared__ float beta_lds[4];
    __shared__ float redA[4], redB[4];

    // beta[h'] = qp_h' . bkp_h'  (pos heads) -- wave w computes h' = w
    {
        float v = qpos[(size_t)row * 256 + w * 64 + l] * bkp[w * 64 + l];
#pragma unroll
        for (int sh = 32; sh; sh >>= 1) v += __shfl_xor(v, sh, 64);
        if (l == 0) beta_lds[w] = v;
    }

    // ---- Pass 1 ----
    {
        f32x4 sacc[2] = {{0.f,0.f,0.f,0.f},{0.f,0.f,0.f,0.f}};
        f32x4 gacc[2][16];
#pragma unroll
        for (int mt = 0; mt < 2; ++mt)
#pragma unroll
            for (int nt = 0; nt < 16; ++nt) gacc[mt][nt] = (f32x4){0.f,0.f,0.f,0.f};
        const float* Rbase = rel + (size_t)row * 128 * 256;
        for (int cs = 0; cs < 8; ++cs) {
            int c0 = cs * 32;
            bf16x8 ua = frag_bf16(u_buf + ((size_t)row * 4 + (p & 3)) * 256 + c0 + g * 8);
            bf16x8 r0 = frag_f32(Rbase + (size_t)(w * 32 + p) * 256 + c0 + g * 8);
            bf16x8 r1 = frag_f32(Rbase + (size_t)(w * 32 + 16 + p) * 256 + c0 + g * 8);
            sacc[0] = MFMA16(ua, r0, sacc[0]);   // D[hp][k]
            sacc[1] = MFMA16(ua, r1, sacc[1]);
#pragma unroll
            for (int nt = 0; nt < 16; ++nt) {
                bf16x8 wv = frag_bf16(WvpT + (size_t)(nt * 16 + p) * 256 + c0 + g * 8);
                gacc[0][nt] = MFMA16(r0, wv, gacc[0][nt]);   // D[k][e]
                gacc[1][nt] = MFMA16(r1, wv, gacc[1][nt]);
            }
        }
        if (g == 0) {   // S_pos rows 0..3 live in lane group 0
#pragma unroll
            for (int mt = 0; mt < 2; ++mt)
#pragma unroll
                for (int i = 0; i < 4; ++i)
                    s_lds[w * 32 + mt * 16 + p][4 + i] = sacc[mt][i];
        }
#pragma unroll
        for (int mt = 0; mt < 2; ++mt) {
            int kbase = w * 32 + mt * 16 + g * 4;      // 4 contiguous k
            int kb8 = kbase >> 3, klo = kbase & 7;
#pragma unroll
            for (int nt = 0; nt < 16; ++nt) {
                int e = nt * 16 + p;
                bf16x4 v;
                v[0] = (__bf16)gacc[mt][nt][0]; v[1] = (__bf16)gacc[mt][nt][1];
                v[2] = (__bf16)gacc[mt][nt][2]; v[3] = (__bf16)gacc[mt][nt][3];
                *(bf16x4*)&Gt[e * 128 + ((kb8 ^ (e & 7)) << 3) + klo] = v;
            }
        }
    }
    // content scores -> s_lds cols 0..3
    {
        const float* sc = s_con + (size_t)(b * 4) * 16384 + qi * 128;
#pragma unroll
        for (int i = 0; i < 2; ++i) {
            int idx = t + i * 256;
            int h = idx >> 7, k = idx & 127;
            s_lds[k][h] = sc[(size_t)h * 16384 + k];
        }
    }
    __syncthreads();

    // ---- softmax per head over k ----
    {
        int h = t >> 5, l32 = t & 31;
        float beta = (h >= 4) ? beta_lds[h - 4] : 0.f;
        float v0 = (s_lds[l32][h] + beta) * 0.125f;
        float v1 = (s_lds[l32 + 32][h] + beta) * 0.125f;
        float v2 = (s_lds[l32 + 64][h] + beta) * 0.125f;
        float v3 = (s_lds[l32 + 96][h] + beta) * 0.125f;
        float m = fmaxf(fmaxf(v0, v1), fmaxf(v2, v3));
#pragma unroll
        for (int sh = 16; sh; sh >>= 1) m = fmaxf(m, __shfl_xor(m, sh, 64));
        v0 = __expf(v0 - m); v1 = __expf(v1 - m);
        v2 = __expf(v2 - m); v3 = __expf(v3 - m);
        float s = v0 + v1 + v2 + v3;
#pragma unroll
        for (int sh = 16; sh; sh >>= 1) s += __shfl_xor(s, sh, 64);
        float inv = 1.0f / s;
        A_lds[h * 136 + l32]      = (__bf16)(v0 * inv);
        A_lds[h * 136 + l32 + 32] = (__bf16)(v1 * inv);
        A_lds[h * 136 + l32 + 64] = (__bf16)(v2 * inv);
        A_lds[h * 136 + l32 + 96] = (__bf16)(v3 * inv);
    }
    __syncthreads();

    // ---- Pass 2: O = A.(Vb) + A.(G) ; wave w covers e in [64w, 64w+64) ----
    {
        f32x4 oacc[4] = {{0.f,0.f,0.f,0.f},{0.f,0.f,0.f,0.f},{0.f,0.f,0.f,0.f},{0.f,0.f,0.f,0.f}};
        const __bf16* vbase = vbT + (size_t)b * 256 * 128;
#pragma unroll
        for (int ks = 0; ks < 4; ++ks) {
            bf16x8 af = frag_bf16(A_lds + p * 136 + ks * 32 + g * 8);
#pragma unroll
            for (int nt = 0; nt < 4; ++nt) {
                int e = w * 64 + nt * 16 + p;
                bf16x8 vf = frag_bf16(vbase + (size_t)e * 128 + ks * 32 + g * 8);
                oacc[nt] = MFMA16(af, vf, oacc[nt]);
                bf16x8 gf = frag_bf16(&Gt[e * 128 + (((ks * 4 + g) ^ (e & 7)) << 3)]);
                oacc[nt] = MFMA16(af, gf, oacc[nt]);
            }
        }
#pragma unroll
        for (int nt = 0; nt < 4; ++nt) {
            int h = w * 2 + (nt >> 1);          // = e>>5 for this n-tile
            if (g == (h >> 2)) {
                int i = h & 3;
                float v = (i == 0) ? oacc[nt][0] : (i == 1) ? oacc[nt][1]
                        : (i == 2) ? oacc[nt][2] : oacc[nt][3];
                out_lds[w * 64 + nt * 16 + p] = v;
            }
        }
    }
    __syncthreads();

    // ---- residual + LayerNorm1 ----
    {
        float y = src[(size_t)row * 256 + t] + out_lds[t] + bvp[t];
        float s1 = y, s2 = y * y;
#pragma unroll
        for (int sh = 32; sh; sh >>= 1) {
            s1 += __shfl_xor(s1, sh, 64);
            s2 += __shfl_xor(s2, sh, 64);
        }
        if (l == 0) { redA[w] = s1; redB[w] = s2; }
        __syncthreads();
        s1 = redA[0] + redA[1] + redA[2] + redA[3];
        s2 = redB[0] + redB[1] + redB[2] + redB[3];
        float mean = s1 * (1.0f / 256.0f);
        float var = fmaxf(s2 * (1.0f / 256.0f) - mean * mean, 0.0f);
        float inv = rsqrtf(var + 1e-5f);
        x_out[(size_t)row * 256 + t] = (y - mean) * inv * g1[t] + be1[t];
    }
}

// ---------------------------------------------------------------------------
// FFN fused: per block (32 rows x 256 hidden chunk):
//   h = relu(x@W1c + b1c) in LDS (bf16), part = h@W2c (fp32 partials).
// grid (32, 8).
// ---------------------------------------------------------------------------
__global__ __launch_bounds__(256) void ffn_mfma(
    const float* __restrict__ x, const __bf16* __restrict__ W1T,
    const float* __restrict__ b1, const __bf16* __restrict__ W2T,
    float* __restrict__ part)
{
    __shared__ __bf16 h_lds[32 * 264];
    int t = threadIdx.x, w = t >> 6, l = t & 63;
    int p = l & 15, g = l >> 4;
    int m0 = blockIdx.x * 32;
    int c0 = blockIdx.y * 256;
    int mt = w & 1, nh = w >> 1;   // wave's m-tile and n-half

    {   // phase A
        f32x4 acc[8];
#pragma unroll
        for (int nt = 0; nt < 8; ++nt) acc[nt] = (f32x4){0.f,0.f,0.f,0.f};
#pragma unroll
        for (int ks = 0; ks < 8; ++ks) {
            bf16x8 a = frag_f32(x + (size_t)(m0 + mt * 16 + p) * 256 + ks * 32 + g * 8);
#pragma unroll
            for (int nt = 0; nt < 8; ++nt) {
                bf16x8 bb = frag_bf16(W1T + (size_t)(c0 + nh * 128 + nt * 16 + p) * 256 + ks * 32 + g * 8);
                acc[nt] = MFMA16(a, bb, acc[nt]);
            }
        }
#pragma unroll
        for (int nt = 0; nt < 8; ++nt) {
            int col = nh * 128 + nt * 16 + p;
            float bv = b1[c0 + col];
#pragma unroll
            for (int i = 0; i < 4; ++i)
                h_lds[(mt * 16 + g * 4 + i) * 264 + col] =
                    (__bf16)fmaxf(acc[nt][i] + bv, 0.f);
        }
    }
    __syncthreads();
    {   // phase B
        f32x4 acc[8];
#pragma unroll
        for (int nt = 0; nt < 8; ++nt) acc[nt] = (f32x4){0.f,0.f,0.f,0.f};
#pragma unroll
        for (int ks = 0; ks < 8; ++ks) {
            bf16x8 a = frag_bf16(h_lds + (mt * 16 + p) * 264 + ks * 32 + g * 8);
#pragma unroll
            for (int nt = 0; nt < 8; ++nt) {
                bf16x8 bb = frag_bf16(W2T + (size_t)(nh * 128 + nt * 16 + p) * 2048 + c0 + ks * 32 + g * 8);
                acc[nt] = MFMA16(a, bb, acc[nt]);
            }
        }
#pragma unroll
        for (int nt = 0; nt < 8; ++nt) {
            int e = nh * 128 + nt * 16 + p;
#pragma unroll
            for (int i = 0; i < 4; ++i)
                part[((size_t)blockIdx.y * NROW + m0 + mt * 16 + g * 4 + i) * 256 + e] = acc[nt][i];
        }
    }
}

// ---------------------------------------------------------------------------
// LN2: out = LN(x + sum_8 part + b2). Block: 4 rows, grid 256.
// ---------------------------------------------------------------------------
__global__ __launch_bounds__(256) void ffn_ln2_kernel(
    const float* __restrict__ x, const float* __restrict__ part,
    const float* __restrict__ b2, const float* __restrict__ g2,
    const float* __restrict__ be2, float* __restrict__ out)
{
    __shared__ float red1[4][4], red2[4][4];
    const int t = threadIdx.x;
    const int r0 = blockIdx.x * 4;
    const int wv = t >> 6, lane = t & 63;
    float b2v = b2[t];
    float yv[4];
#pragma unroll
    for (int r = 0; r < 4; ++r) {
        size_t idx = (size_t)(r0 + r) * 256 + t;
        float y = x[idx] + b2v;
#pragma unroll
        for (int c = 0; c < 8; ++c) y += part[idx + (size_t)c * (NROW * 256)];
        yv[r] = y;
        float s1 = y, s2 = y * y;
#pragma unroll
        for (int sh = 32; sh; sh >>= 1) {
            s1 += __shfl_xor(s1, sh, 64);
            s2 += __shfl_xor(s2, sh, 64);
        }
        if (lane == 0) { red1[r][wv] = s1; red2[r][wv] = s2; }
    }
    __syncthreads();
    float g = g2[t], be = be2[t];
#pragma unroll
    for (int r = 0; r < 4; ++r) {
        float s1 = red1[r][0] + red1[r][1] + red1[r][2] + red1[r][3];
        float s2 = red2[r][0] + red2[r][1] + red2[r][2] + red2[r][3];
        float mean = s1 * (1.0f / 256.0f);
        float var = fmaxf(s2 * (1.0f / 256.0f) - mean * mean, 0.0f);
        float inv = rsqrtf(var + 1e-5f);
        out[(size_t)(r0 + r) * 256 + t] = (yv[r] - mean) * inv * g + be;
    }
}

// ---------------------------------------------------------------------------
extern "C" void kernel_launch(void* const* d_in, const int* in_sizes, int n_in,
                              void* d_out, int out_size, void* d_ws, size_t ws_size,
                              hipStream_t stream)
{
    const float* src  = (const float*)d_in[0];
    const float* spe  = (const float*)d_in[1];
    const float* rel  = (const float*)d_in[2];
    const float* Wq   = (const float*)d_in[3];
    const float* bq   = (const float*)d_in[4];
    const float* Wk   = (const float*)d_in[5];
    const float* bk   = (const float*)d_in[6];
    const float* Wv   = (const float*)d_in[7];
    const float* bv   = (const float*)d_in[8];
    const float* Wqp  = (const float*)d_in[9];
    const float* bqp  = (const float*)d_in[10];
    const float* Wkp  = (const float*)d_in[11];
    const float* bkp  = (const float*)d_in[12];
    const float* Wvp  = (const float*)d_in[13];
    const float* bvp  = (const float*)d_in[14];
    const float* W1   = (const float*)d_in[15];
    const float* b1   = (const float*)d_in[16];
    const float* W2   = (const float*)d_in[17];
    const float* b2   = (const float*)d_in[18];
    const float* g1   = (const float*)d_in[19];
    const float* be1  = (const float*)d_in[20];
    const float* g2   = (const float*)d_in[21];
    const float* be2  = (const float*)d_in[22];

    char* wsb = (char*)d_ws;
    const size_t MB = 1 << 20;
    float*  xbuf  = (float*)(wsb);                       // 0..1MB
    float*  q     = (float*)(wsb + 1 * MB);
    float*  kbuf  = (float*)(wsb + 2 * MB);
    float*  qpos  = (float*)(wsb + 3 * MB);
    __bf16* u_buf = (__bf16*)(wsb + 4 * MB);             // 2MB
    float*  s_con = (float*)(wsb + 6 * MB);              // 2MB
    __bf16* vbT   = (__bf16*)(wsb + 8 * MB);             // 512KB
    __bf16* WqT   = (__bf16*)(wsb + 8 * MB + 512 * 1024);
    __bf16* WkT   = WqT + 65536;
    __bf16* WqpT  = WkT + 65536;
    __bf16* WvT   = WqpT + 65536;
    __bf16* WvpT  = WvT + 65536;                         // ends at 9.125MB
    __bf16* W1T   = (__bf16*)(wsb + 9 * MB + 128 * 1024);    // 1MB
    __bf16* W2T   = (__bf16*)(wsb + 10 * MB + 128 * 1024);   // 1MB
    // FFN partials overlay q..WvT region (dead after attn): 1MB..9MB
    float*  part  = (float*)(wsb + 1 * MB);

    prep_transpose_kernel<<<336, 256, 0, stream>>>(Wq, Wk, Wqp, Wv, Wvp, W1, W2,
                                                   WqT, WkT, WqpT, WvT, WvpT, W1T, W2T);
    proj3_mfma<<<dim3(16, 4, 3), 256, 0, stream>>>(src, spe, WqT, WkT, WqpT,
                                                   bq, bk, bqp, q, kbuf, qpos);
    projv_mfma<<<dim3(16, 4), 256, 0, stream>>>(kbuf, WvT, bv, vbT);
    u_mfma<<<dim3(64, 4), 256, 0, stream>>>(qpos, Wkp, u_buf);
    con_mfma<<<dim3(8, 4), 256, 0, stream>>>(q, kbuf, s_con);
    attn_mfma<<<dim3(kA, kB), 256, 0, stream>>>(src, rel, u_buf, s_con, vbT, WvpT,
                                                qpos, bkp, bvp, g1, be1, xbuf);
    ffn_mfma<<<dim3(32, 8), 256, 0, stream>>>(xbuf, W1T, b1, W2T, part);
    ffn_ln2_kernel<<<256, 256, 0, stream>>>(xbuf, part, b2, g2, be2, (float*)d_out);
}

// Round 5
// 349.653 us; speedup vs baseline: 1.5219x; 1.0065x over previous
//
#include <hip/hip_runtime.h>
#include <hip/hip_bf16.h>
#include <math.h>

#define kB 8
#define kA 128
#define kD 256
#define kF 2048
#define NROW 1024

typedef __attribute__((ext_vector_type(8))) __bf16 bf16x8;
typedef __attribute__((ext_vector_type(4))) float f32x4;

#define MFMA16(a, b, c) __builtin_amdgcn_mfma_f32_16x16x32_bf16(a, b, c, 0, 0, 0)

// Fragment loaders. A-frag: lane m=l&15 holds row m, k = (l>>4)*8+j.
// B-frag: lane n=l&15 holds col n, k likewise. C/D: col n=l&15, row m=(l>>4)*4+i.
__device__ __forceinline__ bf16x8 frag_f32(const float* p) {
    float4 a = *(const float4*)p;
    float4 b = *(const float4*)(p + 4);
    bf16x8 v;
    v[0] = (__bf16)a.x; v[1] = (__bf16)a.y; v[2] = (__bf16)a.z; v[3] = (__bf16)a.w;
    v[4] = (__bf16)b.x; v[5] = (__bf16)b.y; v[6] = (__bf16)b.z; v[7] = (__bf16)b.w;
    return v;
}
__device__ __forceinline__ bf16x8 frag_bf16(const __bf16* p) {
    return *(const bf16x8*)p;
}

// ---------------------------------------------------------------------------
// prep1: transpose + cvt weights to bf16: out[C][R] = (bf16) in[R][C].
// {Wq,Wk,Wv,Wvp} 16 tiles each (64), W1 128 tiles, W2 128 tiles. 320 blocks.
// ---------------------------------------------------------------------------
__global__ __launch_bounds__(256) void prep1_kernel(
    const float* __restrict__ Wq, const float* __restrict__ Wk,
    const float* __restrict__ Wv, const float* __restrict__ Wvp,
    const float* __restrict__ W1, const float* __restrict__ W2,
    __bf16* WqT, __bf16* WkT, __bf16* WvT, __bf16* WvpT,
    __bf16* W1T, __bf16* W2T)
{
    int bid = blockIdx.x;
    const float* in; __bf16* out; int R, C;
    if (bid < 64) {
        int m = bid >> 4; bid &= 15;
        const float* ins[4] = {Wq, Wk, Wv, Wvp};
        __bf16* outs[4] = {WqT, WkT, WvT, WvpT};
        in = ins[m]; out = outs[m]; R = 256; C = 256;
    } else if (bid < 192) { bid -= 64; in = W1; out = W1T; R = 256; C = 2048; }
    else { bid -= 192; in = W2; out = W2T; R = 2048; C = 256; }
    int tilesC = C >> 6;
    int r0 = (bid / tilesC) << 6, c0 = (bid % tilesC) << 6;
    __shared__ float tile[64][65];
    int t = threadIdx.x, tr = t >> 6, tc = t & 63;
#pragma unroll
    for (int i = 0; i < 16; ++i)
        tile[tr + i * 4][tc] = in[(size_t)(r0 + tr + i * 4) * C + c0 + tc];
    __syncthreads();
#pragma unroll
    for (int i = 0; i < 16; ++i) {
        int oc = tr + i * 4;
        out[(size_t)(c0 + oc) * R + r0 + tc] = (__bf16)tile[tc][oc];
    }
}

// ---------------------------------------------------------------------------
// prep2: M_hT[h][c][d] = sum_e Wqp[d][h*64+e] * Wkp[c][h*64+e]  (bf16),
// plus ubias[h][c] = sum_e bqp[h*64+e] * Wkp[c][h*64+e].
// Grid 17: blocks 0..15 MFMA (h = bid>>2, c-block = bid&3), block 16 = ubias.
// ---------------------------------------------------------------------------
__global__ __launch_bounds__(256) void prep2_kernel(
    const float* __restrict__ Wqp, const float* __restrict__ Wkp,
    const float* __restrict__ bqp, __bf16* __restrict__ M_hT,
    float* __restrict__ ubias)
{
    int bid = blockIdx.x;
    int t = threadIdx.x;
    if (bid < 16) {
        int h = bid >> 2, cb = bid & 3;
        int w = t >> 6, l = t & 63, p = l & 15, g = l >> 4;
        int m0 = cb * 64 + w * 16;
        f32x4 acc[16];
#pragma unroll
        for (int nt = 0; nt < 16; ++nt) acc[nt] = (f32x4){0.f, 0.f, 0.f, 0.f};
#pragma unroll
        for (int ks = 0; ks < 2; ++ks) {
            bf16x8 a = frag_f32(Wkp + (size_t)(m0 + p) * 256 + h * 64 + ks * 32 + g * 8);
#pragma unroll
            for (int nt = 0; nt < 16; ++nt) {
                bf16x8 bb = frag_f32(Wqp + (size_t)(nt * 16 + p) * 256 + h * 64 + ks * 32 + g * 8);
                acc[nt] = MFMA16(a, bb, acc[nt]);
            }
        }
#pragma unroll
        for (int nt = 0; nt < 16; ++nt)
#pragma unroll
            for (int i = 0; i < 4; ++i)
                M_hT[((size_t)h * 256 + m0 + g * 4 + i) * 256 + nt * 16 + p] = (__bf16)acc[nt][i];
    } else {
        int c = t;
#pragma unroll
        for (int h = 0; h < 4; ++h) {
            float s = 0.f;
            for (int e = 0; e < 64; ++e) s += bqp[h * 64 + e] * Wkp[(size_t)c * 256 + h * 64 + e];
            ubias[h * 256 + c] = s;
        }
    }
}

// ---------------------------------------------------------------------------
// proj: z=0: q = src@Wq+bq ; z=1: kb = src@Wk+bk  (fp32 out). grid (16,4,2).
// ---------------------------------------------------------------------------
__global__ __launch_bounds__(256) void proj_kernel(
    const float* __restrict__ src,
    const __bf16* __restrict__ WqT, const __bf16* __restrict__ WkT,
    const float* __restrict__ bq, const float* __restrict__ bk,
    float* __restrict__ q, float* __restrict__ kb)
{
    const __bf16* WT; const float* bias; float* Y;
    if (blockIdx.z == 0) { WT = WqT; bias = bq; Y = q; }
    else                 { WT = WkT; bias = bk; Y = kb; }
    int t = threadIdx.x, w = t >> 6, l = t & 63;
    int p = l & 15, g = l >> 4;
    int m0 = blockIdx.x * 64 + w * 16;
    int n0 = blockIdx.y * 64;
    f32x4 acc[4];
#pragma unroll
    for (int nt = 0; nt < 4; ++nt) acc[nt] = (f32x4){0.f, 0.f, 0.f, 0.f};
#pragma unroll
    for (int ks = 0; ks < 8; ++ks) {
        bf16x8 a = frag_f32(src + (size_t)(m0 + p) * 256 + ks * 32 + g * 8);
#pragma unroll
        for (int nt = 0; nt < 4; ++nt) {
            bf16x8 bb = frag_bf16(WT + (size_t)(n0 + nt * 16 + p) * 256 + ks * 32 + g * 8);
            acc[nt] = MFMA16(a, bb, acc[nt]);
        }
    }
#pragma unroll
    for (int nt = 0; nt < 4; ++nt) {
        int col = n0 + nt * 16 + p;
        float bv = bias[col];
#pragma unroll
        for (int i = 0; i < 4; ++i)
            Y[(size_t)(m0 + g * 4 + i) * 256 + col] = acc[nt][i] + bv;
    }
}

// ---------------------------------------------------------------------------
// projv: vb = kb@Wv + bv, stored TRANSPOSED bf16: vbT[b][e][k]. grid (16,4).
// ---------------------------------------------------------------------------
__global__ __launch_bounds__(256) void projv_kernel(
    const float* __restrict__ kb, const __bf16* __restrict__ WvT,
    const float* __restrict__ bv, __bf16* __restrict__ vbT)
{
    int t = threadIdx.x, w = t >> 6, l = t & 63;
    int p = l & 15, g = l >> 4;
    int m0 = blockIdx.x * 64 + w * 16;
    int n0 = blockIdx.y * 64;
    f32x4 acc[4];
#pragma unroll
    for (int nt = 0; nt < 4; ++nt) acc[nt] = (f32x4){0.f, 0.f, 0.f, 0.f};
#pragma unroll
    for (int ks = 0; ks < 8; ++ks) {
        bf16x8 a = frag_f32(kb + (size_t)(m0 + p) * 256 + ks * 32 + g * 8);
#pragma unroll
        for (int nt = 0; nt < 4; ++nt) {
            bf16x8 bb = frag_bf16(WvT + (size_t)(n0 + nt * 16 + p) * 256 + ks * 32 + g * 8);
            acc[nt] = MFMA16(a, bb, acc[nt]);
        }
    }
#pragma unroll
    for (int nt = 0; nt < 4; ++nt) {
        int e = n0 + nt * 16 + p;
        float bvv = bv[e];
#pragma unroll
        for (int i = 0; i < 4; ++i) {
            int row = m0 + g * 4 + i;
            vbT[((size_t)(row >> 7) * 256 + e) * 128 + (row & 127)] = (__bf16)(acc[nt][i] + bvv);
        }
    }
}

// ---------------------------------------------------------------------------
// u: u_buf[bq][h][c] = spe @ M_hT + ubias  (bf16). grid (16 m-blocks, 4 h).
// ---------------------------------------------------------------------------
__global__ __launch_bounds__(256) void u_kernel(
    const float* __restrict__ spe, const __bf16* __restrict__ M_hT,
    const float* __restrict__ ubias, __bf16* __restrict__ u_buf)
{
    int t = threadIdx.x, w = t >> 6, l = t & 63;
    int p = l & 15, g = l >> 4;
    int h = blockIdx.y;
    int m0 = blockIdx.x * 64 + w * 16;
    f32x4 acc[16];
#pragma unroll
    for (int nt = 0; nt < 16; ++nt) acc[nt] = (f32x4){0.f, 0.f, 0.f, 0.f};
#pragma unroll
    for (int ks = 0; ks < 8; ++ks) {
        bf16x8 a = frag_f32(spe + (size_t)(m0 + p) * 256 + ks * 32 + g * 8);
#pragma unroll
        for (int nt = 0; nt < 16; ++nt) {
            bf16x8 bb = frag_bf16(M_hT + ((size_t)h * 256 + nt * 16 + p) * 256 + ks * 32 + g * 8);
            acc[nt] = MFMA16(a, bb, acc[nt]);
        }
    }
#pragma unroll
    for (int nt = 0; nt < 16; ++nt) {
        float ub = ubias[h * 256 + nt * 16 + p];
#pragma unroll
        for (int i = 0; i < 4; ++i)
            u_buf[((size_t)(m0 + g * 4 + i) * 4 + h) * 256 + nt * 16 + p] = (__bf16)(acc[nt][i] + ub);
    }
}

// ---------------------------------------------------------------------------
// attn1: per (b,q): S_pos = U.R^T (MFMA), content = q.kb (MFMA, bcast-A),
// R staged bf16 into swizzled-transposable LDS; softmax; r = attn.R (MFMA).
// Outputs: A_all[b][h][q][k] bf16 probs, r_all[bq][h][c] bf16.
// 512 threads (8 waves), one block per (b,q); 2 blocks/CU (LDS ~73KB).
// ---------------------------------------------------------------------------
__global__ __launch_bounds__(512, 4) void attn1_kernel(
    const float* __restrict__ rel, const float* __restrict__ q,
    const float* __restrict__ kb, const __bf16* __restrict__ u_buf,
    __bf16* __restrict__ A_all, __bf16* __restrict__ r_all)
{
    const int t = threadIdx.x, w = t >> 6, l = t & 63;
    const int p = l & 15, g = l >> 4;
    const int qi = blockIdx.x, b = blockIdx.y;
    const int row = b * 128 + qi;

    __shared__ __bf16 RT[32768];        // 64KB: [c=256][k=128], k-octet XOR-swizzled by c&7
    __shared__ __bf16 A_lds[16 * 136];  // [h(16, 8 used)][k=128], pitch 136
    __shared__ float s_lds[128][9];     // [k][h]

    // zero A rows 8..15 (r-GEMM A-frag safety)
    for (int i = t; i < 8 * 136; i += 512) A_lds[8 * 136 + i] = (__bf16)0.f;

    // ---- pass 1: S_pos + content scores + RT staging ----
    {
        const float* Rbase = rel + (size_t)row * 128 * 256;
        const int k = w * 16 + p;        // this lane's R row (n-dim)
        const int ko = k >> 3, klo = (k & 7) * 2;
        f32x4 sacc = (f32x4){0.f, 0.f, 0.f, 0.f};
#pragma unroll
        for (int cs = 0; cs < 8; ++cs) {
            int c0 = cs * 32 + g * 8;
            bf16x8 rf = frag_f32(Rbase + (size_t)k * 256 + c0);
            bf16x8 ua = frag_bf16(u_buf + ((size_t)row * 4 + (p & 3)) * 256 + c0);
            sacc = MFMA16(ua, rf, sacc);
#pragma unroll
            for (int j = 0; j < 8; ++j) {
                int byte = (c0 + j) * 256 + ((ko ^ j) << 4) + klo;
                *(__bf16*)((char*)RT + byte) = rf[j];
            }
        }
        f32x4 cacc[4];
#pragma unroll
        for (int h = 0; h < 4; ++h) cacc[h] = (f32x4){0.f, 0.f, 0.f, 0.f};
#pragma unroll
        for (int h = 0; h < 4; ++h)
#pragma unroll
            for (int ks = 0; ks < 2; ++ks) {
                bf16x8 qa = frag_f32(q + (size_t)row * 256 + h * 64 + ks * 32 + g * 8);
                bf16x8 kf = frag_f32(kb + ((size_t)b * 128 + k) * 256 + h * 64 + ks * 32 + g * 8);
                cacc[h] = MFMA16(qa, kf, cacc[h]);
            }
        if (g == 0) {
#pragma unroll
            for (int i = 0; i < 4; ++i) s_lds[k][4 + i] = sacc[i];
#pragma unroll
            for (int h = 0; h < 4; ++h) s_lds[k][h] = cacc[h][0];
        }
    }
    __syncthreads();

    // ---- softmax: wave w = head w over k=128 ----
    {
        float v0 = s_lds[l][w] * 0.125f;
        float v1 = s_lds[l + 64][w] * 0.125f;
        float m = fmaxf(v0, v1);
#pragma unroll
        for (int sh = 32; sh; sh >>= 1) m = fmaxf(m, __shfl_xor(m, sh, 64));
        v0 = __expf(v0 - m); v1 = __expf(v1 - m);
        float s = v0 + v1;
#pragma unroll
        for (int sh = 32; sh; sh >>= 1) s += __shfl_xor(s, sh, 64);
        float inv = 1.0f / s;
        __bf16 e0 = (__bf16)(v0 * inv), e1 = (__bf16)(v1 * inv);
        A_lds[w * 136 + l] = e0;
        A_lds[w * 136 + l + 64] = e1;
        __bf16* Ag = A_all + ((size_t)(b * 8 + w) * 128 + qi) * 128;
        Ag[l] = e0; Ag[l + 64] = e1;
    }
    __syncthreads();

    // ---- r-GEMM: r[h][c] = sum_k attn[h][k] R[k][c]; wave w: c in [32w, 32w+32) ----
    {
        f32x4 racc[2];
        racc[0] = (f32x4){0.f, 0.f, 0.f, 0.f};
        racc[1] = (f32x4){0.f, 0.f, 0.f, 0.f};
#pragma unroll
        for (int ks = 0; ks < 4; ++ks) {
            bf16x8 af = *(const bf16x8*)&A_lds[p * 136 + ks * 32 + g * 8];
#pragma unroll
            for (int nt = 0; nt < 2; ++nt) {
                int c = w * 32 + nt * 16 + p;
                bf16x8 bfr = *(const bf16x8*)((char*)RT + c * 256 + (((ks * 4 + g) ^ (c & 7)) << 4));
                racc[nt] = MFMA16(af, bfr, racc[nt]);
            }
        }
        if (g < 2) {
#pragma unroll
            for (int nt = 0; nt < 2; ++nt)
#pragma unroll
                for (int i = 0; i < 4; ++i)
                    r_all[((size_t)row * 8 + g * 4 + i) * 256 + w * 32 + nt * 16 + p] =
                        (__bf16)racc[nt][i];
        }
    }
}

// ---------------------------------------------------------------------------
// attn2: out rows (4 per block): O = attn.Vb + r.Wvp ; + src + bvp ; LN1.
// grid 256 x 256 thr. Wave w covers e in [64w, 64w+64).
// ---------------------------------------------------------------------------
__global__ __launch_bounds__(256) void attn2_kernel(
    const float* __restrict__ src, const __bf16* __restrict__ A_all,
    const __bf16* __restrict__ r_all, const __bf16* __restrict__ vbT,
    const __bf16* __restrict__ WvpT, const float* __restrict__ bvp,
    const float* __restrict__ g1, const float* __restrict__ be1,
    float* __restrict__ x_out)
{
    const int t = threadIdx.x, w = t >> 6, l = t & 63;
    const int p = l & 15, g = l >> 4;
    const int r0 = blockIdx.x * 4;
    const int b = r0 >> 7, q0 = r0 & 127;
    __shared__ float ymem[4][260];

    f32x4 oacc[4];
#pragma unroll
    for (int nt = 0; nt < 4; ++nt) oacc[nt] = (f32x4){0.f, 0.f, 0.f, 0.f};
#pragma unroll
    for (int nt = 0; nt < 4; ++nt) {
        int e0 = w * 64 + nt * 16;
        int h = e0 >> 5;
        // content PV: contract k=128
#pragma unroll
        for (int ks = 0; ks < 4; ++ks) {
            bf16x8 af = frag_bf16(A_all + ((size_t)(b * 8 + h) * 128 + q0 + p) * 128 + ks * 32 + g * 8);
            bf16x8 vf = frag_bf16(vbT + ((size_t)b * 256 + e0 + p) * 128 + ks * 32 + g * 8);
            oacc[nt] = MFMA16(af, vf, oacc[nt]);
        }
        // pos PV: contract c=256
#pragma unroll
        for (int cs = 0; cs < 8; ++cs) {
            bf16x8 rf = frag_bf16(r_all + ((size_t)(r0 + p) * 8 + h) * 256 + cs * 32 + g * 8);
            bf16x8 wf = frag_bf16(WvpT + (size_t)(e0 + p) * 256 + cs * 32 + g * 8);
            oacc[nt] = MFMA16(rf, wf, oacc[nt]);
        }
    }
    if (g == 0) {
#pragma unroll
        for (int nt = 0; nt < 4; ++nt)
#pragma unroll
            for (int i = 0; i < 4; ++i)
                ymem[i][w * 64 + nt * 16 + p] = oacc[nt][i];
    }
    __syncthreads();

    // LN1: wave w handles row w
    {
        float vals[4];
        float s1 = 0.f, s2 = 0.f;
#pragma unroll
        for (int j = 0; j < 4; ++j) {
            int e = l + j * 64;
            float v = src[(size_t)(r0 + w) * 256 + e] + ymem[w][e] + bvp[e];
            vals[j] = v; s1 += v; s2 += v * v;
        }
#pragma unroll
        for (int sh = 32; sh; sh >>= 1) {
            s1 += __shfl_xor(s1, sh, 64);
            s2 += __shfl_xor(s2, sh, 64);
        }
        float mean = s1 * (1.0f / 256.0f);
        float var = fmaxf(s2 * (1.0f / 256.0f) - mean * mean, 0.0f);
        float inv = rsqrtf(var + 1e-5f);
#pragma unroll
        for (int j = 0; j < 4; ++j) {
            int e = l + j * 64;
            x_out[(size_t)(r0 + w) * 256 + e] = (vals[j] - mean) * inv * g1[e] + be1[e];
        }
    }
}

// ---------------------------------------------------------------------------
// ffn: block = 16 rows x 256-hidden chunk. PhaseA: h=relu(x@W1c+b1c) -> LDS
// bf16. PhaseB: part[chunk] = h @ W2c. grid (64, 8).
// ---------------------------------------------------------------------------
__global__ __launch_bounds__(256) void ffn_kernel(
    const float* __restrict__ x, const __bf16* __restrict__ W1T,
    const float* __restrict__ b1, const __bf16* __restrict__ W2T,
    float* __restrict__ part)
{
    __shared__ __bf16 h_lds[16 * 264];
    int t = threadIdx.x, w = t >> 6, l = t & 63;
    int p = l & 15, g = l >> 4;
    int m0 = blockIdx.x * 16;
    int c0 = blockIdx.y * 256;

    {
        f32x4 acc[4];
#pragma unroll
        for (int nt = 0; nt < 4; ++nt) acc[nt] = (f32x4){0.f, 0.f, 0.f, 0.f};
#pragma unroll
        for (int ks = 0; ks < 8; ++ks) {
            bf16x8 a = frag_f32(x + (size_t)(m0 + p) * 256 + ks * 32 + g * 8);
#pragma unroll
            for (int nt = 0; nt < 4; ++nt) {
                int hc = w * 64 + nt * 16 + p;
                bf16x8 bb = frag_bf16(W1T + (size_t)(c0 + hc) * 256 + ks * 32 + g * 8);
                acc[nt] = MFMA16(a, bb, acc[nt]);
            }
        }
#pragma unroll
        for (int nt = 0; nt < 4; ++nt) {
            int hc = w * 64 + nt * 16 + p;
            float bv = b1[c0 + hc];
#pragma unroll
            for (int i = 0; i < 4; ++i)
                h_lds[(g * 4 + i) * 264 + hc] = (__bf16)fmaxf(acc[nt][i] + bv, 0.f);
        }
    }
    __syncthreads();
    {
        f32x4 acc[4];
#pragma unroll
        for (int nt = 0; nt < 4; ++nt) acc[nt] = (f32x4){0.f, 0.f, 0.f, 0.f};
#pragma unroll
        for (int ks = 0; ks < 8; ++ks) {
            bf16x8 a = *(const bf16x8*)&h_lds[p * 264 + ks * 32 + g * 8];
#pragma unroll
            for (int nt = 0; nt < 4; ++nt) {
                int e = w * 64 + nt * 16 + p;
                bf16x8 bb = frag_bf16(W2T + (size_t)e * 2048 + c0 + ks * 32 + g * 8);
                acc[nt] = MFMA16(a, bb, acc[nt]);
            }
        }
#pragma unroll
        for (int nt = 0; nt < 4; ++nt)
#pragma unroll
            for (int i = 0; i < 4; ++i)
                part[((size_t)blockIdx.y * NROW + m0 + g * 4 + i) * 256 + w * 64 + nt * 16 + p] =
                    acc[nt][i];
    }
}

// ---------------------------------------------------------------------------
// ln2: out = LN(x + sum_8 part + b2). Block: 4 rows, grid 256.
// ---------------------------------------------------------------------------
__global__ __launch_bounds__(256) void ffn_ln2_kernel(
    const float* __restrict__ x, const float* __restrict__ part,
    const float* __restrict__ b2, const float* __restrict__ g2,
    const float* __restrict__ be2, float* __restrict__ out)
{
    __shared__ float red1[4][4], red2[4][4];
    const int t = threadIdx.x;
    const int r0 = blockIdx.x * 4;
    const int wv = t >> 6, lane = t & 63;
    float b2v = b2[t];
    float yv[4];
#pragma unroll
    for (int r = 0; r < 4; ++r) {
        size_t idx = (size_t)(r0 + r) * 256 + t;
        float y = x[idx] + b2v;
#pragma unroll
        for (int c = 0; c < 8; ++c) y += part[idx + (size_t)c * (NROW * 256)];
        yv[r] = y;
        float s1 = y, s2 = y * y;
#pragma unroll
        for (int sh = 32; sh; sh >>= 1) {
            s1 += __shfl_xor(s1, sh, 64);
            s2 += __shfl_xor(s2, sh, 64);
        }
        if (lane == 0) { red1[r][wv] = s1; red2[r][wv] = s2; }
    }
    __syncthreads();
    float g = g2[t], be = be2[t];
#pragma unroll
    for (int r = 0; r < 4; ++r) {
        float s1 = red1[r][0] + red1[r][1] + red1[r][2] + red1[r][3];
        float s2 = red2[r][0] + red2[r][1] + red2[r][2] + red2[r][3];
        float mean = s1 * (1.0f / 256.0f);
        float var = fmaxf(s2 * (1.0f / 256.0f) - mean * mean, 0.0f);
        float inv = rsqrtf(var + 1e-5f);
        out[(size_t)(r0 + r) * 256 + t] = (yv[r] - mean) * inv * g + be;
    }
}

// ---------------------------------------------------------------------------
extern "C" void kernel_launch(void* const* d_in, const int* in_sizes, int n_in,
                              void* d_out, int out_size, void* d_ws, size_t ws_size,
                              hipStream_t stream)
{
    const float* src  = (const float*)d_in[0];
    const float* spe  = (const float*)d_in[1];
    const float* rel  = (const float*)d_in[2];
    const float* Wq   = (const float*)d_in[3];
    const float* bq   = (const float*)d_in[4];
    const float* Wk   = (const float*)d_in[5];
    const float* bk   = (const float*)d_in[6];
    const float* Wv   = (const float*)d_in[7];
    const float* bv   = (const float*)d_in[8];
    const float* Wqp  = (const float*)d_in[9];
    const float* bqp  = (const float*)d_in[10];
    const float* Wkp  = (const float*)d_in[11];
    const float* bkp  = (const float*)d_in[12];   // cancels in softmax (const in k)
    const float* Wvp  = (const float*)d_in[13];
    const float* bvp  = (const float*)d_in[14];
    const float* W1   = (const float*)d_in[15];
    const float* b1   = (const float*)d_in[16];
    const float* W2   = (const float*)d_in[17];
    const float* b2   = (const float*)d_in[18];
    const float* g1   = (const float*)d_in[19];
    const float* be1  = (const float*)d_in[20];
    const float* g2   = (const float*)d_in[21];
    const float* be2  = (const float*)d_in[22];
    (void)bkp;

    char* wsb = (char*)d_ws;
    const size_t MB = 1 << 20;
    float*  xbuf  = (float*)(wsb);                     // 0..1MB
    float*  q     = (float*)(wsb + 1 * MB);            // 1MB
    float*  kb    = (float*)(wsb + 2 * MB);            // 1MB
    __bf16* A_all = (__bf16*)(wsb + 3 * MB);           // 2MB
    __bf16* r_all = (__bf16*)(wsb + 5 * MB);           // 4MB
    float*  part  = (float*)(wsb + 1 * MB);            // overlay 1..9MB (dead after attn2)
    __bf16* u_buf = (__bf16*)(wsb + 9 * MB);           // 2MB
    __bf16* vbT   = (__bf16*)(wsb + 11 * MB);          // 512KB
    __bf16* WqT   = (__bf16*)(wsb + 11 * MB + 512 * 1024);
    __bf16* WkT   = WqT + 65536;
    __bf16* WvT   = WkT + 65536;
    __bf16* WvpT  = WvT + 65536;                       // ends 12MB
    __bf16* W1T   = (__bf16*)(wsb + 12 * MB);          // 1MB
    __bf16* W2T   = (__bf16*)(wsb + 13 * MB);          // 1MB
    __bf16* M_hT  = (__bf16*)(wsb + 14 * MB);          // 512KB
    float*  ubias = (float*)(wsb + 14 * MB + 512 * 1024);  // 4KB

    prep1_kernel<<<320, 256, 0, stream>>>(Wq, Wk, Wv, Wvp, W1, W2,
                                          WqT, WkT, WvT, WvpT, W1T, W2T);
    prep2_kernel<<<17, 256, 0, stream>>>(Wqp, Wkp, bqp, M_hT, ubias);
    proj_kernel<<<dim3(16, 4, 2), 256, 0, stream>>>(src, WqT, WkT, bq, bk, q, kb);
    projv_kernel<<<dim3(16, 4), 256, 0, stream>>>(kb, WvT, bv, vbT);
    u_kernel<<<dim3(16, 4), 256, 0, stream>>>(spe, M_hT, ubias, u_buf);
    attn1_kernel<<<dim3(kA, kB), 512, 0, stream>>>(rel, q, kb, u_buf, A_all, r_all);
    attn2_kernel<<<256, 256, 0, stream>>>(src, A_all, r_all, vbT, WvpT, bvp,
                                          g1, be1, xbuf);
    ffn_kernel<<<dim3(64, 8), 256, 0, stream>>>(xbuf, W1T, b1, W2T, part);
    ffn_ln2_kernel<<<256, 256, 0, stream>>>(xbuf, part, b2, g2, be2, (float*)d_out);
}